// Round 19
// baseline (265.177 us; speedup 1.0000x reference)
//
#include <hip/hip_runtime.h>
#include <hip/hip_bf16.h>

#define NN 50000      // nodes
#define NE 500000     // edges (without self loops)
#define EP (NE + NN)  // edges with self loops
#define NB 50         // graphs
#define NEG 0.2f
#define NBKT 196        // ceil(NN/256) dst buckets (dst>>8)
#define CAP 3584        // per-bucket capacity (mean 2806 + ~14 sigma, incl 16 pad)
#define CHUNK 2048      // edges per bucket_kernel block
#define NBLK1 ((EP + CHUNK - 1) / CHUNK)
#define NTILES 3125     // NN/16 exactly: 16-row tiles for the GEMM
#define GEMM_GX 782     // grid.x for grid-stride GEMM (~4 tiles/block)

// setup_kernel grid partition
#define ENC_BLKS 12500   // NN*64/256 exactly
#define MEAN_BLKS 256
#define WCONV_BLKS 640
#define ZERO_BLKS 51     // ceil((NB*256+NB)/256)
#define SETUP_GRID (ENC_BLKS + MEAN_BLKS + WCONV_BLKS + 1 + ZERO_BLKS)

typedef __attribute__((ext_vector_type(8))) short short8;
typedef __attribute__((ext_vector_type(4))) float f32x4;

__device__ __forceinline__ ushort f2bf(float f) {
  unsigned u = __float_as_uint(f);
  unsigned r = (u + 0x7FFFu + ((u >> 16) & 1u)) >> 16;
  return (ushort)r;
}
__device__ __forceinline__ float bf2f(ushort b) {
  return __uint_as_float(((unsigned)b) << 16);
}

// hardware exp2 (v_exp_f32 is 2^x); s_nop covers the trans->VALU wait state
__device__ __forceinline__ float exp2s(float x) {
  float r;
  asm("v_exp_f32 %0, %1\ns_nop 0" : "=v"(r) : "v"(x));
  return r;
}

// all-lanes sum within each 16-lane row (head group), pure-VALU DPP
__device__ __forceinline__ float row_reduce16(float x) {
  x += __int_as_float(__builtin_amdgcn_mov_dpp(__float_as_int(x), 0xB1, 0xF, 0xF, true));
  x += __int_as_float(__builtin_amdgcn_mov_dpp(__float_as_int(x), 0x4E, 0xF, 0xF, true));
  x += __int_as_float(__builtin_amdgcn_mov_dpp(__float_as_int(x), 0x124, 0xF, 0xF, true));
  x += __int_as_float(__builtin_amdgcn_mov_dpp(__float_as_int(x), 0x128, 0xF, 0xF, true));
  return x;
}

// ================= mega setup: encoder + mean-partials + wconv + att/gcursor +
// zero(sums,cnts) — all input-only dependencies, one launch =================
__global__ __launch_bounds__(256) void setup_kernel(
    const float* __restrict__ x, const float* __restrict__ enc_w,
    const float* __restrict__ enc_b, ushort* __restrict__ h0,
    const float* __restrict__ ea, float* __restrict__ partials,
    const float* __restrict__ g1_wl, const float* __restrict__ g1_wr,
    const float* __restrict__ g2_wl, const float* __restrict__ g2_wr,
    ushort* __restrict__ w1l, ushort* __restrict__ w1r,
    ushort* __restrict__ w2l, ushort* __restrict__ w2r,
    const float* __restrict__ att1, const float* __restrict__ att2,
    float* __restrict__ a06_1, float* __restrict__ a04_1,
    float* __restrict__ a06_2, float* __restrict__ a04_2,
    int* __restrict__ gcursor, float* __restrict__ zero_region) {
  __shared__ float sw[4];
  int b = blockIdx.x, t = threadIdx.x;
  if (b < ENC_BLKS) {  // ---- encoder: h0 = relu(x @ enc_w + enc_b), bf16 ----
    int i = b * 256 + t;  // exactly NN*64
    int n = i >> 6, j = i & 63;
    float acc = enc_b[j];
#pragma unroll
    for (int k = 0; k < 8; k++) acc += x[n * 8 + k] * enc_w[k * 64 + j];
    h0[i] = f2bf(fmaxf(acc, 0.f));
    return;
  }
  b -= ENC_BLKS;
  if (b < MEAN_BLKS) {  // ---- edge_attr mean partial sums (no atomics) ----
    int idx = b * 256 + t;
    float v = 0.f;
    for (int i = idx; i < NE; i += 65536) v += ea[i];
    for (int off = 1; off < 64; off <<= 1) v += __shfl_xor(v, off, 64);
    if ((t & 63) == 0) sw[t >> 6] = v;
    __syncthreads();
    if (t == 0) partials[b] = sw[0] + sw[1] + sw[2] + sw[3];
    return;
  }
  b -= MEAN_BLKS;
  if (b < WCONV_BLKS) {  // ---- weight converts f32 [K][256] -> bf16 [256][K] ----
    if (b < 128) {
      int sec = b >> 6;
      const float* W = sec ? g1_wr : g1_wl;
      ushort* Wt = sec ? w1r : w1l;
      int i = (b & 63) * 256 + t;
      int n = i >> 6, k = i & 63;
      Wt[i] = f2bf(W[(size_t)k * 256 + n]);
    } else {
      int bb = b - 128;
      int sec = bb >> 8;
      const float* W = sec ? g2_wr : g2_wl;
      ushort* Wt = sec ? w2r : w2l;
      int i = (bb & 255) * 256 + t;
      int n = i >> 8, k = i & 255;
      Wt[i] = f2bf(W[(size_t)k * 256 + n]);
    }
    return;
  }
  b -= WCONV_BLKS;
  if (b == 0) {  // ---- att pre-scale + gcursor init ----
    const float L2E = 1.44269504f;
    float v1 = att1[t], v2 = att2[t];
    a06_1[t] = 0.6f * L2E * v1;
    a04_1[t] = 0.4f * L2E * v1;
    a06_2[t] = 0.6f * L2E * v2;
    a04_2[t] = 0.4f * L2E * v2;
    if (t < NBKT) gcursor[t] = t * CAP;
    return;
  }
  b -= 1;
  {  // ---- zero sums+cnts (contiguous region of NB*256+NB floats) ----
    int i = b * 256 + t;
    if (i < NB * 256 + NB) zero_region[i] = 0.f;
  }
}

// ---------- pass 1: bucket edges by dst>>8 (LDS histogram; 196 global
// fetch-adds per block for region reservation; no per-edge global atomics) ----------
__global__ __launch_bounds__(256) void bucket_kernel(const int* __restrict__ ei,
                                                     const float* __restrict__ ea,
                                                     const float* __restrict__ partials,
                                                     int* __restrict__ gcursor,
                                                     int2* __restrict__ bucketed) {
  __shared__ int hist[NBKT];
  __shared__ int lbase[NBKT];
  __shared__ float smean[4];
  int t = threadIdx.x;
  int e0 = blockIdx.x * CHUNK;
  // mean from 256 partials (each thread one, reduce)
  float pv = partials[t];
  for (int off = 1; off < 64; off <<= 1) pv += __shfl_xor(pv, off, 64);
  if ((t & 63) == 0) smean[t >> 6] = pv;
  for (int i = t; i < NBKT; i += 256) hist[i] = 0;
  __syncthreads();
  float mean = (smean[0] + smean[1] + smean[2] + smean[3]) * (1.0f / NE);
  int packed[8], eab[8], bkt[8];
#pragma unroll
  for (int j = 0; j < 8; j++) {
    int e = e0 + j * 256 + t;
    bool valid = e < EP;
    int src, dst;
    float v;
    if (e < NE) {
      src = ei[e];
      dst = ei[NE + e];
      v = ea[e];
    } else {
      int n = valid ? (e - NE) : 0;
      src = dst = n;
      v = mean;
    }
    bkt[j] = valid ? (dst >> 8) : -1;
    packed[j] = src | ((dst & 255) << 16);
    eab[j] = __float_as_int(v);
    if (valid) atomicAdd(&hist[dst >> 8], 1);
  }
  __syncthreads();
  for (int i = t; i < NBKT; i += 256)
    lbase[i] = hist[i] ? atomicAdd(&gcursor[i], hist[i]) : 0;
  __syncthreads();
#pragma unroll
  for (int j = 0; j < 8; j++) {
    if (bkt[j] >= 0) {
      int pos = atomicAdd(&lbase[bkt[j]], 1);
      pos = min(pos, (bkt[j] + 1) * CAP - 1);  // overflow guard (never expected)
      bucketed[pos] = make_int2(packed[j], eab[j]);
    }
  }
}

// ---------- pass 2: per-bucket counting sort by dst&255 (all-LDS), emits
// final sedge (src pre-scaled to byte offset, 16 pad entries per bucket so
// the gat kernel can run a branchless 2-deep pipeline) ----------
__global__ __launch_bounds__(256) void bucket_sort_kernel(const int* __restrict__ gcursor,
                                                          const int2* __restrict__ bucketed,
                                                          int2* __restrict__ sedge,
                                                          int* __restrict__ offsets,
                                                          int* __restrict__ counts) {
  __shared__ int2 stage[CAP];
  __shared__ int hist[256], scn[256], cur[256];
  int b = blockIdx.x, t = threadIdx.x;
  int base = b * CAP;
  int nb = min(gcursor[b] - base, CAP - 16);
  hist[t] = 0;
  for (int i = t; i < nb; i += 256) stage[i] = bucketed[base + i];
  __syncthreads();
  // pad entries [nb, nb+16): duplicates of a valid in-bucket edge (masked in gat)
  if (t < 16) {
    int2 pv = make_int2((stage[0].x & 0xFFFF) << 9, stage[0].y);
    sedge[base + nb + t] = pv;
  }
  for (int i = t; i < nb; i += 256) atomicAdd(&hist[(stage[i].x >> 16) & 255], 1);
  __syncthreads();
  int v = hist[t];
  scn[t] = v;
  __syncthreads();
  for (int off = 1; off < 256; off <<= 1) {
    int add = (t >= off) ? scn[t - off] : 0;
    __syncthreads();
    scn[t] += add;
    __syncthreads();
  }
  int excl = scn[t] - v;
  cur[t] = excl;
  __syncthreads();
  for (int i = t; i < nb; i += 256) {
    int dl = (stage[i].x >> 16) & 255;
    int p = atomicAdd(&cur[dl], 1);
    // src pre-scaled to byte offset within xl (src * 256 ushorts * 2B = src<<9)
    sedge[base + p] = make_int2((stage[i].x & 0xFFFF) << 9, stage[i].y);
  }
  int d = b * 256 + t;
  if (d < NN) {
    offsets[d] = base + excl;
    counts[d] = v;
  }
}

// ---------- dual linear via MFMA: 16-row tiles, low-VGPR, grid-stride ----------
// R18 post-mortem: 32-row tile needs 128 VGPR -> 16% occupancy -> 8% MfmaUtil
// (latency-serialized). Shrink per-wave M to 16 rows (acc 16 + A 16 + B 32
// VGPR ~ 90 total) so 5-6 waves/SIMD can be resident; NN = 16*3125 exactly,
// so all row bounds checks drop out. B stays L1-hot across ~4 grid-stride
// tiles per block.
template <int K>
__global__ __launch_bounds__(256) void dual_linear_pb(const ushort* __restrict__ A,
                                                      const ushort* __restrict__ Wl,
                                                      const ushort* __restrict__ Wr,
                                                      const float* __restrict__ bl,
                                                      const float* __restrict__ br,
                                                      ushort* __restrict__ xl,
                                                      ushort* __restrict__ xr) {
  __shared__ ushort lt[16][272];  // swizzled cols; rows 16B-aligned (544B stride)
  int wave = threadIdx.x >> 6, lane = threadIdx.x & 63;
  int lr = lane & 15;        // row-in-frag (A) / col-in-frag (B/D)
  int kb = (lane >> 4) * 8;  // k-base within 32-wide k-step
  const ushort* W = blockIdx.y ? Wr : Wl;
  const float* bias = blockIdx.y ? br : bl;
  ushort* O = blockIdx.y ? xr : xl;
  const int c0 = wave * 64;
  const ushort* pb = W + (size_t)(c0 + lr) * K + kb;
  int tid = threadIdx.x;
  int cb = (tid & 31) * 8;  // col base for the coalesced write phase

  for (int t = blockIdx.x; t < NTILES; t += GEMM_GX) {
    int r = t * 16;
    const ushort* pa = A + (size_t)(r + lr) * K + kb;
    f32x4 acc[4];
#pragma unroll
    for (int fc = 0; fc < 4; fc++) acc[fc] = (f32x4){0.f, 0.f, 0.f, 0.f};
#pragma unroll
    for (int kc = 0; kc < K; kc += 64) {
      short8 a0 = *(const short8*)(pa + kc);
      short8 a1 = *(const short8*)(pa + kc + 32);
      short8 b0[4], b1[4];
#pragma unroll
      for (int fc = 0; fc < 4; fc++) {
        b0[fc] = *(const short8*)(pb + (size_t)fc * 16 * K + kc);
        b1[fc] = *(const short8*)(pb + (size_t)fc * 16 * K + kc + 32);
      }
#pragma unroll
      for (int fc = 0; fc < 4; fc++)
        acc[fc] = __builtin_amdgcn_mfma_f32_16x16x32_bf16(a0, b0[fc], acc[fc], 0, 0, 0);
#pragma unroll
      for (int fc = 0; fc < 4; fc++)
        acc[fc] = __builtin_amdgcn_mfma_f32_16x16x32_bf16(a1, b1[fc], acc[fc], 0, 0, 0);
    }
    // stage bf16 subtile to LDS, XOR-swizzled: col' = col ^ (((row>>2)&3)<<4)
#pragma unroll
    for (int fc = 0; fc < 4; fc++) {
      int c = c0 + fc * 16 + lr;
      float bv = bias[c];
#pragma unroll
      for (int j = 0; j < 4; j++) {
        int row = (lane >> 4) * 4 + j;
        int cs = c ^ (((row >> 2) & 3) << 4);
        lt[row][cs] = f2bf(acc[fc][j] + bv);
      }
    }
    __syncthreads();
    // coalesced write: 256 threads x 2 iters; each row written as contiguous 512B
#pragma unroll
    for (int it = 0; it < 2; it++) {
      int rl = (tid >> 5) + it * 8;
      int cs = cb ^ (((rl >> 2) & 3) << 4);
      short8 v = *(const short8*)&lt[rl][cs];
      *(short8*)(O + (size_t)(r + rl) * 256 + cb) = v;
    }
    __syncthreads();
  }
}

// ================= fused GATv2 edge phase (4-wide, branchless, 2-deep pipe) ====
__global__ __launch_bounds__(256) void gat_fused_kernel(const int* __restrict__ offsets,
                                                        const int* __restrict__ counts,
                                                        const int2* __restrict__ sedge,
                                                        const ushort* __restrict__ xl,
                                                        const ushort* __restrict__ xr,
                                                        const float* __restrict__ we,
                                                        const float* __restrict__ a06p,
                                                        const float* __restrict__ a04p,
                                                        const float* __restrict__ bias,
                                                        ushort* __restrict__ hb) {
  int w = threadIdx.x >> 6, lane = threadIdx.x & 63;
  int d = blockIdx.x * 4 + w;
  if (d >= NN) return;
  int off = offsets[d], cnt = counts[d];
  const int c4 = lane * 4;
  ushort4 xru = *(const ushort4*)(xr + (size_t)d * 256 + c4);
  const float4 xr4 = {bf2f(xru.x), bf2f(xru.y), bf2f(xru.z), bf2f(xru.w)};
  const float4 we4 = *(const float4*)(we + c4);
  const float4 a06 = *(const float4*)(a06p + c4);
  const float4 a04 = *(const float4*)(a04p + c4);
  float4 acc = {0.f, 0.f, 0.f, 0.f};
  float den = 0.f;
  const int2* pe = sedge + off;
  const char* xlc = (const char*)xl + (size_t)c4 * 2;  // sedge.x is byte offset
  // pipeline: e/xu = current iter, f/yu = next iter (all reads valid via pads)
  int2 e0 = pe[0], e1 = pe[1], e2 = pe[2], e3 = pe[3];
  ushort4 xu0 = *(const ushort4*)(xlc + (size_t)(unsigned)e0.x);
  ushort4 xu1 = *(const ushort4*)(xlc + (size_t)(unsigned)e1.x);
  ushort4 xu2 = *(const ushort4*)(xlc + (size_t)(unsigned)e2.x);
  ushort4 xu3 = *(const ushort4*)(xlc + (size_t)(unsigned)e3.x);
  int2 f0 = pe[4], f1 = pe[5], f2 = pe[6], f3 = pe[7];
  ushort4 yu0 = *(const ushort4*)(xlc + (size_t)(unsigned)f0.x);
  ushort4 yu1 = *(const ushort4*)(xlc + (size_t)(unsigned)f1.x);
  ushort4 yu2 = *(const ushort4*)(xlc + (size_t)(unsigned)f2.x);
  ushort4 yu3 = *(const ushort4*)(xlc + (size_t)(unsigned)f3.x);
#pragma unroll 2
  for (int i = 0; i < cnt; i += 4) {
    float ce0 = __int_as_float(e0.y), ce1 = __int_as_float(e1.y);
    float ce2 = __int_as_float(e2.y), ce3 = __int_as_float(e3.y);
    float4 x0 = {bf2f(xu0.x), bf2f(xu0.y), bf2f(xu0.z), bf2f(xu0.w)};
    float4 x1 = {bf2f(xu1.x), bf2f(xu1.y), bf2f(xu1.z), bf2f(xu1.w)};
    float4 x2 = {bf2f(xu2.x), bf2f(xu2.y), bf2f(xu2.z), bf2f(xu2.w)};
    float4 x3 = {bf2f(xu3.x), bf2f(xu3.y), bf2f(xu3.z), bf2f(xu3.w)};
    // rotate pipeline (renamed away under unroll) and prefetch slots i+8..i+11
    e0 = f0; e1 = f1; e2 = f2; e3 = f3;
    xu0 = yu0; xu1 = yu1; xu2 = yu2; xu3 = yu3;
    f0 = pe[i + 8]; f1 = pe[i + 9]; f2 = pe[i + 10]; f3 = pe[i + 11];
    yu0 = *(const ushort4*)(xlc + (size_t)(unsigned)f0.x);
    yu1 = *(const ushort4*)(xlc + (size_t)(unsigned)f1.x);
    yu2 = *(const ushort4*)(xlc + (size_t)(unsigned)f2.x);
    yu3 = *(const ushort4*)(xlc + (size_t)(unsigned)f3.x);
    float v0, v1, v2, v3;
    float p0, p1, p2, p3;
    v0 = x0.x + fmaf(ce0, we4.x, xr4.x);
    v1 = x0.y + fmaf(ce0, we4.y, xr4.y);
    v2 = x0.z + fmaf(ce0, we4.z, xr4.z);
    v3 = x0.w + fmaf(ce0, we4.w, xr4.w);
    p0 = fmaf(a06.x, v0, a04.x * fabsf(v0));
    p0 = fmaf(a06.y, v1, fmaf(a04.y, fabsf(v1), p0));
    p0 = fmaf(a06.z, v2, fmaf(a04.z, fabsf(v2), p0));
    p0 = fmaf(a06.w, v3, fmaf(a04.w, fabsf(v3), p0));
    v0 = x1.x + fmaf(ce1, we4.x, xr4.x);
    v1 = x1.y + fmaf(ce1, we4.y, xr4.y);
    v2 = x1.z + fmaf(ce1, we4.z, xr4.z);
    v3 = x1.w + fmaf(ce1, we4.w, xr4.w);
    p1 = fmaf(a06.x, v0, a04.x * fabsf(v0));
    p1 = fmaf(a06.y, v1, fmaf(a04.y, fabsf(v1), p1));
    p1 = fmaf(a06.z, v2, fmaf(a04.z, fabsf(v2), p1));
    p1 = fmaf(a06.w, v3, fmaf(a04.w, fabsf(v3), p1));
    v0 = x2.x + fmaf(ce2, we4.x, xr4.x);
    v1 = x2.y + fmaf(ce2, we4.y, xr4.y);
    v2 = x2.z + fmaf(ce2, we4.z, xr4.z);
    v3 = x2.w + fmaf(ce2, we4.w, xr4.w);
    p2 = fmaf(a06.x, v0, a04.x * fabsf(v0));
    p2 = fmaf(a06.y, v1, fmaf(a04.y, fabsf(v1), p2));
    p2 = fmaf(a06.z, v2, fmaf(a04.z, fabsf(v2), p2));
    p2 = fmaf(a06.w, v3, fmaf(a04.w, fabsf(v3), p2));
    v0 = x3.x + fmaf(ce3, we4.x, xr4.x);
    v1 = x3.y + fmaf(ce3, we4.y, xr4.y);
    v2 = x3.z + fmaf(ce3, we4.z, xr4.z);
    v3 = x3.w + fmaf(ce3, we4.w, xr4.w);
    p3 = fmaf(a06.x, v0, a04.x * fabsf(v0));
    p3 = fmaf(a06.y, v1, fmaf(a04.y, fabsf(v1), p3));
    p3 = fmaf(a06.z, v2, fmaf(a04.z, fabsf(v2), p3));
    p3 = fmaf(a06.w, v3, fmaf(a04.w, fabsf(v3), p3));
    p0 = row_reduce16(p0);
    p1 = row_reduce16(p1);
    p2 = row_reduce16(p2);
    p3 = row_reduce16(p3);
    float ex0 = exp2s(fminf(p0, 120.f));
    float ex1 = exp2s(fminf(p1, 120.f));
    float ex2 = exp2s(fminf(p2, 120.f));
    float ex3 = exp2s(fminf(p3, 120.f));
    ex1 = (i + 1 < cnt) ? ex1 : 0.f;  // wave-uniform tail masks
    ex2 = (i + 2 < cnt) ? ex2 : 0.f;
    ex3 = (i + 3 < cnt) ? ex3 : 0.f;
    den += (ex0 + ex1) + (ex2 + ex3);
    acc.x = fmaf(x0.x, ex0, fmaf(x1.x, ex1, fmaf(x2.x, ex2, fmaf(x3.x, ex3, acc.x))));
    acc.y = fmaf(x0.y, ex0, fmaf(x1.y, ex1, fmaf(x2.y, ex2, fmaf(x3.y, ex3, acc.y))));
    acc.z = fmaf(x0.z, ex0, fmaf(x1.z, ex1, fmaf(x2.z, ex2, fmaf(x3.z, ex3, acc.z))));
    acc.w = fmaf(x0.w, ex0, fmaf(x1.w, ex1, fmaf(x2.w, ex2, fmaf(x3.w, ex3, acc.w))));
  }
  const float4 b4 = *(const float4*)(bias + c4);
  float inv = 1.f / den;  // every node has a self-loop -> den > 0
  ushort4 o;
  o.x = f2bf(fmaxf(fmaf(acc.x, inv, b4.x), 0.f));
  o.y = f2bf(fmaxf(fmaf(acc.y, inv, b4.y), 0.f));
  o.z = f2bf(fmaxf(fmaf(acc.z, inv, b4.z), 0.f));
  o.w = f2bf(fmaxf(fmaf(acc.w, inv, b4.w), 0.f));
  *(ushort4*)(hb + (size_t)d * 256 + c4) = o;
}

// ---------- global mean pool (batch is sorted; run-length flush) ----------
__global__ __launch_bounds__(256) void pool_kernel(const ushort* __restrict__ h,
                                                   const int* __restrict__ batch,
                                                   float* __restrict__ sums,
                                                   float* __restrict__ cnts) {
  __shared__ int sb[128];
  int n0 = blockIdx.x * 128;
  int j = threadIdx.x;
  int count = min(128, NN - n0);
  if (count <= 0) return;
  for (int t = threadIdx.x; t < count; t += 256) sb[t] = batch[n0 + t];
  __syncthreads();
  float acc = 0.f;
  int run = 0;
  int cur = sb[0];
  for (int i = 0; i < count; ++i) {
    int b = sb[i];
    if (b != cur) {
      atomicAdd(&sums[(size_t)cur * 256 + j], acc);
      if (j == 0) atomicAdd(&cnts[cur], (float)run);
      acc = 0.f;
      run = 0;
      cur = b;
    }
    acc += bf2f(h[(size_t)(n0 + i) * 256 + j]);
    run++;
  }
  atomicAdd(&sums[(size_t)cur * 256 + j], acc);
  if (j == 0) atomicAdd(&cnts[cur], (float)run);
}

// ---------- post-MLP head: one block per graph ----------
__global__ __launch_bounds__(128) void head_kernel(const float* __restrict__ sums,
                                                   const float* __restrict__ cnts,
                                                   const float* __restrict__ p1_w,
                                                   const float* __restrict__ p1_b,
                                                   const float* __restrict__ ln_g,
                                                   const float* __restrict__ ln_b,
                                                   const float* __restrict__ p2_w,
                                                   const float* __restrict__ p2_b,
                                                   const float* __restrict__ hc_w,
                                                   const float* __restrict__ hc_b,
                                                   const float* __restrict__ hf_w,
                                                   const float* __restrict__ hf_b,
                                                   float* __restrict__ out) {
  int g = blockIdx.x;
  int j = threadIdx.x;  // 0..127
  __shared__ float sp[256], st[128], sz[64];
  float cnt = fmaxf(cnts[g], 1.0f);
  for (int t = j; t < 256; t += 128) sp[t] = sums[(size_t)g * 256 + t] / cnt;
  __syncthreads();
  float acc = p1_b[j];
  for (int k = 0; k < 256; k++) acc += sp[k] * p1_w[(size_t)k * 128 + j];
  st[j] = acc;
  __syncthreads();
  float mu = 0.f;
  for (int k = 0; k < 128; k++) mu += st[k];
  mu *= (1.f / 128.f);
  float var = 0.f;
  for (int k = 0; k < 128; k++) {
    float d = st[k] - mu;
    var += d * d;
  }
  var *= (1.f / 128.f);
  float tj = (acc - mu) * rsqrtf(var + 1e-5f) * ln_g[j] + ln_b[j];
  tj = fmaxf(tj, 0.f);
  __syncthreads();
  st[j] = tj;
  __syncthreads();
  if (j < 64) {
    float z = p2_b[j];
    for (int k = 0; k < 128; k++) z += st[k] * p2_w[(size_t)k * 64 + j];
    z = fmaxf(z, 0.f);
    sz[j] = z;
    out[500 + (size_t)g * 64 + j] = z;  // output 2: z [B,64]
  }
  __syncthreads();
  if (j == 0) {
    float c = hc_b[0];
    for (int k = 0; k < 64; k++) c += sz[k] * hc_w[k];
    out[g] = c;  // output 0: cooling [B]
  }
  if (j >= 1 && j < 10) {
    int f = j - 1;
    float v = hf_b[f];
    for (int k = 0; k < 64; k++) v += sz[k] * hf_w[(size_t)k * 9 + f];
    out[50 + (size_t)g * 9 + f] = v;  // output 1: fatigue [B,9]
  }
}

extern "C" void kernel_launch(void* const* d_in, const int* in_sizes, int n_in,
                              void* d_out, int out_size, void* d_ws, size_t ws_size,
                              hipStream_t stream) {
  const float* x = (const float*)d_in[0];
  const int* ei = (const int*)d_in[1];
  const float* ea = (const float*)d_in[2];
  const int* batch = (const int*)d_in[3];
  const float* enc_w = (const float*)d_in[4];
  const float* enc_b = (const float*)d_in[5];
  const float* g1_wl = (const float*)d_in[6];
  const float* g1_bl = (const float*)d_in[7];
  const float* g1_wr = (const float*)d_in[8];
  const float* g1_br = (const float*)d_in[9];
  const float* g1_we = (const float*)d_in[10];
  const float* g1_att = (const float*)d_in[11];
  const float* g1_bias = (const float*)d_in[12];
  const float* g2_wl = (const float*)d_in[13];
  const float* g2_bl = (const float*)d_in[14];
  const float* g2_wr = (const float*)d_in[15];
  const float* g2_br = (const float*)d_in[16];
  const float* g2_we = (const float*)d_in[17];
  const float* g2_att = (const float*)d_in[18];
  const float* g2_bias = (const float*)d_in[19];
  const float* p1_w = (const float*)d_in[20];
  const float* p1_b = (const float*)d_in[21];
  const float* ln_g = (const float*)d_in[22];
  const float* ln_b = (const float*)d_in[23];
  const float* p2_w = (const float*)d_in[24];
  const float* p2_b = (const float*)d_in[25];
  const float* hc_w = (const float*)d_in[26];
  const float* hc_b = (const float*)d_in[27];
  const float* hf_w = (const float*)d_in[28];
  const float* hf_b = (const float*)d_in[29];
  float* out = (float*)d_out;

  // ---- workspace layout ----
  ushort* xlb = (ushort*)d_ws;                    // N*256 bf16
  ushort* xrb = xlb + (size_t)NN * 256;           // N*256 bf16
  ushort* hb = xrb + (size_t)NN * 256;            // N*256 bf16
  ushort* h0b = hb + (size_t)NN * 256;            // N*64 bf16
  ushort* w1l = h0b + (size_t)NN * 64;            // 256*64 bf16 (transposed)
  ushort* w1r = w1l + 256 * 64;
  ushort* w2l = w1r + 256 * 64;                   // 256*256 bf16
  ushort* w2r = w2l + 256 * 256;
  int2* bucketed = (int2*)(w2r + 256 * 256);      // NBKT*CAP (pass-1 output)
  int2* sedge = bucketed + (size_t)NBKT * CAP;    // NBKT*CAP (sorted + pads)
  int* gcursor = (int*)(sedge + (size_t)NBKT * CAP);  // NBKT
  int* counts = gcursor + NBKT;                   // NN
  int* offsets = counts + NN;                     // NN
  float* sums = (float*)(offsets + NN);           // B*256 (zeroed in setup)
  float* cnts = sums + (size_t)NB * 256;          // B    (zeroed in setup)
  float* partials = cnts + NB;                    // 256
  float* a06_1 = partials + 256;                  // 256
  float* a04_1 = a06_1 + 256;                     // 256
  float* a06_2 = a04_1 + 256;                     // 256
  float* a04_2 = a06_2 + 256;                     // 256

  // ---- mega setup (encoder, mean partials, wconv, att, gcursor, zeros) ----
  setup_kernel<<<SETUP_GRID, 256, 0, stream>>>(
      x, enc_w, enc_b, h0b, ea, partials, g1_wl, g1_wr, g2_wl, g2_wr, w1l, w1r,
      w2l, w2r, g1_att, g2_att, a06_1, a04_1, a06_2, a04_2, gcursor, sums);

  // ---- two-pass LDS bucket sort of edges by dst ----
  bucket_kernel<<<NBLK1, 256, 0, stream>>>(ei, ea, partials, gcursor, bucketed);
  bucket_sort_kernel<<<NBKT, 256, 0, stream>>>(gcursor, bucketed, sedge, offsets, counts);

  const dim3 gemmGrid(GEMM_GX, 2);
  const int nGatBlocks = (NN + 3) / 4;

  // ================= GAT layer 1 (K=64) =================
  dual_linear_pb<64><<<gemmGrid, 256, 0, stream>>>(h0b, w1l, w1r, g1_bl, g1_br, xlb, xrb);
  gat_fused_kernel<<<nGatBlocks, 256, 0, stream>>>(offsets, counts, sedge, xlb, xrb,
                                                   g1_we, a06_1, a04_1, g1_bias, hb);

  // ================= GAT layer 2 (K=256) =================
  dual_linear_pb<256><<<gemmGrid, 256, 0, stream>>>(hb, w2l, w2r, g2_bl, g2_br, xlb, xrb);
  gat_fused_kernel<<<nGatBlocks, 256, 0, stream>>>(offsets, counts, sedge, xlb, xrb,
                                                   g2_we, a06_2, a04_2, g2_bias, hb);

  // ================= pool + head =================
  pool_kernel<<<(NN + 127) / 128, 256, 0, stream>>>(hb, batch, sums, cnts);
  head_kernel<<<NB, 128, 0, stream>>>(sums, cnts, p1_w, p1_b, ln_g, ln_b, p2_w, p2_b,
                                      hc_w, hc_b, hf_w, hf_b, out);
}

// Round 20
// 251.460 us; speedup vs baseline: 1.0545x; 1.0545x over previous
//
#include <hip/hip_runtime.h>
#include <hip/hip_bf16.h>

#define NN 50000      // nodes
#define NE 500000     // edges (without self loops)
#define EP (NE + NN)  // edges with self loops
#define NB 50         // graphs
#define NEG 0.2f
#define NBKT 196        // ceil(NN/256) dst buckets (dst>>8)
#define CAP 3584        // per-bucket capacity (mean 2806 + ~14 sigma, incl 16 pad)
#define CHUNK 2048      // edges per bucket block
#define NBLK1 ((EP + CHUNK - 1) / CHUNK)  // 269 bucket blocks
#define NTILES 1563     // ceil(NN/32) row tiles for the GEMM
#define GEMM_GX 392     // grid.x for grid-stride GEMM (R16 optimum: ~4 tiles/block)
#define SELF_FLAG (1 << 24)  // marks self-loop edges awaiting mean-ea patch

// setup_kernel grid partition: bucket + mean first (critical path to sort)
#define MEAN_BLKS 256
#define ENC_BLKS 12500   // NN*64/256 exactly
#define WCONV_BLKS 640
#define ZERO_BLKS 51     // ceil((NB*256+NB)/256)
#define SETUP_GRID (NBLK1 + MEAN_BLKS + ENC_BLKS + WCONV_BLKS + 1 + ZERO_BLKS)

typedef __attribute__((ext_vector_type(8))) short short8;
typedef __attribute__((ext_vector_type(4))) float f32x4;

__device__ __forceinline__ ushort f2bf(float f) {
  unsigned u = __float_as_uint(f);
  unsigned r = (u + 0x7FFFu + ((u >> 16) & 1u)) >> 16;
  return (ushort)r;
}
__device__ __forceinline__ float bf2f(ushort b) {
  return __uint_as_float(((unsigned)b) << 16);
}

// hardware exp2 (v_exp_f32 is 2^x); s_nop covers the trans->VALU wait state
__device__ __forceinline__ float exp2s(float x) {
  float r;
  asm("v_exp_f32 %0, %1\ns_nop 0" : "=v"(r) : "v"(x));
  return r;
}

// all-lanes sum within each 16-lane row (head group), pure-VALU DPP
__device__ __forceinline__ float row_reduce16(float x) {
  x += __int_as_float(__builtin_amdgcn_mov_dpp(__float_as_int(x), 0xB1, 0xF, 0xF, true));
  x += __int_as_float(__builtin_amdgcn_mov_dpp(__float_as_int(x), 0x4E, 0xF, 0xF, true));
  x += __int_as_float(__builtin_amdgcn_mov_dpp(__float_as_int(x), 0x124, 0xF, 0xF, true));
  x += __int_as_float(__builtin_amdgcn_mov_dpp(__float_as_int(x), 0x128, 0xF, 0xF, true));
  return x;
}

// ================= mega setup: bucket pass-1 + mean-partials + encoder + wconv
// + att + zero(sums,cnts) — one launch; bucket blocks overlap encoder blocks.
// Self-loop edges are FLAGGED (bit 24) instead of needing the ea-mean here;
// bucket_sort patches them (breaks the mean->bucket serialization).
__global__ __launch_bounds__(256) void setup_kernel(
    const float* __restrict__ x, const float* __restrict__ enc_w,
    const float* __restrict__ enc_b, ushort* __restrict__ h0,
    const float* __restrict__ ea, float* __restrict__ partials,
    const int* __restrict__ ei, int* __restrict__ gcursor,
    int2* __restrict__ bucketed,
    const float* __restrict__ g1_wl, const float* __restrict__ g1_wr,
    const float* __restrict__ g2_wl, const float* __restrict__ g2_wr,
    ushort* __restrict__ w1l, ushort* __restrict__ w1r,
    ushort* __restrict__ w2l, ushort* __restrict__ w2r,
    const float* __restrict__ att1, const float* __restrict__ att2,
    float* __restrict__ a06_1, float* __restrict__ a04_1,
    float* __restrict__ a06_2, float* __restrict__ a04_2,
    float* __restrict__ zero_region) {
  __shared__ float sw[4];
  __shared__ int hist[NBKT];
  __shared__ int lbase[NBKT];
  int b = blockIdx.x, t = threadIdx.x;
  if (b < NBLK1) {  // ---- bucket pass 1: LDS histogram + region reservation ----
    int e0 = b * CHUNK;
    for (int i = t; i < NBKT; i += 256) hist[i] = 0;
    __syncthreads();
    int packed[8], eab[8], bkt[8];
#pragma unroll
    for (int j = 0; j < 8; j++) {
      int e = e0 + j * 256 + t;
      bool valid = e < EP;
      int src, dst, fl = 0;
      float v = 0.f;
      if (e < NE) {
        src = ei[e];
        dst = ei[NE + e];
        v = ea[e];
      } else {
        int n = valid ? (e - NE) : 0;
        src = dst = n;
        fl = SELF_FLAG;  // ea patched to mean in bucket_sort
      }
      bkt[j] = valid ? (dst >> 8) : -1;
      packed[j] = src | ((dst & 255) << 16) | fl;
      eab[j] = __float_as_int(v);
      if (valid) atomicAdd(&hist[dst >> 8], 1);
    }
    __syncthreads();
    for (int i = t; i < NBKT; i += 256)
      lbase[i] = hist[i] ? (i * CAP + atomicAdd(&gcursor[i], hist[i])) : 0;
    __syncthreads();
#pragma unroll
    for (int j = 0; j < 8; j++) {
      if (bkt[j] >= 0) {
        int pos = atomicAdd(&lbase[bkt[j]], 1);
        pos = min(pos, (bkt[j] + 1) * CAP - 1);  // overflow guard (never expected)
        bucketed[pos] = make_int2(packed[j], eab[j]);
      }
    }
    return;
  }
  b -= NBLK1;
  if (b < MEAN_BLKS) {  // ---- edge_attr mean partial sums (no atomics) ----
    int idx = b * 256 + t;
    float v = 0.f;
    for (int i = idx; i < NE; i += 65536) v += ea[i];
    for (int off = 1; off < 64; off <<= 1) v += __shfl_xor(v, off, 64);
    if ((t & 63) == 0) sw[t >> 6] = v;
    __syncthreads();
    if (t == 0) partials[b] = sw[0] + sw[1] + sw[2] + sw[3];
    return;
  }
  b -= MEAN_BLKS;
  if (b < ENC_BLKS) {  // ---- encoder: h0 = relu(x @ enc_w + enc_b), bf16 ----
    int i = b * 256 + t;  // exactly NN*64
    int n = i >> 6, j = i & 63;
    float acc = enc_b[j];
#pragma unroll
    for (int k = 0; k < 8; k++) acc += x[n * 8 + k] * enc_w[k * 64 + j];
    h0[i] = f2bf(fmaxf(acc, 0.f));
    return;
  }
  b -= ENC_BLKS;
  if (b < WCONV_BLKS) {  // ---- weight converts f32 [K][256] -> bf16 [256][K] ----
    if (b < 128) {
      int sec = b >> 6;
      const float* W = sec ? g1_wr : g1_wl;
      ushort* Wt = sec ? w1r : w1l;
      int i = (b & 63) * 256 + t;
      int n = i >> 6, k = i & 63;
      Wt[i] = f2bf(W[(size_t)k * 256 + n]);
    } else {
      int bb = b - 128;
      int sec = bb >> 8;
      const float* W = sec ? g2_wr : g2_wl;
      ushort* Wt = sec ? w2r : w2l;
      int i = (bb & 255) * 256 + t;
      int n = i >> 8, k = i & 255;
      Wt[i] = f2bf(W[(size_t)k * 256 + n]);
    }
    return;
  }
  b -= WCONV_BLKS;
  if (b == 0) {  // ---- att pre-scale ----
    const float L2E = 1.44269504f;
    float v1 = att1[t], v2 = att2[t];
    a06_1[t] = 0.6f * L2E * v1;
    a04_1[t] = 0.4f * L2E * v1;
    a06_2[t] = 0.6f * L2E * v2;
    a04_2[t] = 0.4f * L2E * v2;
    return;
  }
  b -= 1;
  {  // ---- zero sums+cnts (contiguous region of NB*256+NB floats) ----
    int i = b * 256 + t;
    if (i < NB * 256 + NB) zero_region[i] = 0.f;
  }
}

// ---------- pass 2: per-bucket counting sort by dst&255 (all-LDS), emits
// final sedge (src pre-scaled to byte offset, 16 pad entries per bucket).
// Also reduces the 256 mean-partials and patches flagged self-loop ea. ----------
__global__ __launch_bounds__(256) void bucket_sort_kernel(const int* __restrict__ gcursor,
                                                          const float* __restrict__ partials,
                                                          const int2* __restrict__ bucketed,
                                                          int2* __restrict__ sedge,
                                                          int* __restrict__ offsets,
                                                          int* __restrict__ counts) {
  __shared__ int2 stage[CAP];
  __shared__ int hist[256], scn[256], cur[256];
  __shared__ float sw[4];
  int b = blockIdx.x, t = threadIdx.x;
  // mean from 256 partials
  float pv = partials[t];
  for (int off = 1; off < 64; off <<= 1) pv += __shfl_xor(pv, off, 64);
  if ((t & 63) == 0) sw[t >> 6] = pv;
  hist[t] = 0;
  __syncthreads();
  int meanb = __float_as_int((sw[0] + sw[1] + sw[2] + sw[3]) * (1.0f / NE));
  int base = b * CAP;
  int nb = min(gcursor[b], CAP - 16);
  for (int i = t; i < nb; i += 256) {
    int2 s = bucketed[base + i];
    if (s.x & SELF_FLAG) s.y = meanb;  // patch self-loop ea to mean
    stage[i] = s;
  }
  __syncthreads();
  // pad entries [nb, nb+16): duplicates of a valid in-bucket edge (masked in gat)
  if (t < 16) {
    int2 pv2 = make_int2((stage[0].x & 0xFFFF) << 9, stage[0].y);
    sedge[base + nb + t] = pv2;
  }
  for (int i = t; i < nb; i += 256) atomicAdd(&hist[(stage[i].x >> 16) & 255], 1);
  __syncthreads();
  int v = hist[t];
  scn[t] = v;
  __syncthreads();
  for (int off = 1; off < 256; off <<= 1) {
    int add = (t >= off) ? scn[t - off] : 0;
    __syncthreads();
    scn[t] += add;
    __syncthreads();
  }
  int excl = scn[t] - v;
  cur[t] = excl;
  __syncthreads();
  for (int i = t; i < nb; i += 256) {
    int dl = (stage[i].x >> 16) & 255;
    int p = atomicAdd(&cur[dl], 1);
    // src pre-scaled to byte offset within xl (src * 256 ushorts * 2B = src<<9)
    sedge[base + p] = make_int2((stage[i].x & 0xFFFF) << 9, stage[i].y);
  }
  int d = b * 256 + t;
  if (d < NN) {
    offsets[d] = base + excl;
    counts[d] = v;
  }
}

// ---------- dual linear via MFMA: R16 optimum (32-row tiles, K-chunked, GX=392) ----
template <int K>
__global__ __launch_bounds__(256) void dual_linear_pb(const ushort* __restrict__ A,
                                                      const ushort* __restrict__ Wl,
                                                      const ushort* __restrict__ Wr,
                                                      const float* __restrict__ bl,
                                                      const float* __restrict__ br,
                                                      ushort* __restrict__ xl,
                                                      ushort* __restrict__ xr) {
  __shared__ ushort lt[32][272];  // swizzled cols; rows 16B-aligned (544B stride)
  int wave = threadIdx.x >> 6, lane = threadIdx.x & 63;
  int lr = lane & 15;        // row-in-frag (A) / col-in-frag (B/D)
  int kb = (lane >> 4) * 8;  // k-base within 32-wide k-step
  const ushort* W = blockIdx.y ? Wr : Wl;
  const float* bias = blockIdx.y ? br : bl;
  ushort* O = blockIdx.y ? xr : xl;
  const int c0 = wave * 64;
  const ushort* pb = W + (size_t)(c0 + lr) * K + kb;
  int tid = threadIdx.x;
  int cb = (tid & 31) * 8;  // col base for the coalesced write phase

  for (int t = blockIdx.x; t < NTILES; t += GEMM_GX) {
    int r = t * 32;
    int ra0 = min(r + lr, NN - 1);
    int ra1 = min(r + 16 + lr, NN - 1);
    const ushort* pa0 = A + (size_t)ra0 * K + kb;
    const ushort* pa1 = A + (size_t)ra1 * K + kb;
    f32x4 acc[2][4];
#pragma unroll
    for (int fr = 0; fr < 2; fr++)
#pragma unroll
      for (int fc = 0; fc < 4; fc++) acc[fr][fc] = (f32x4){0.f, 0.f, 0.f, 0.f};
#pragma unroll
    for (int kc = 0; kc < K; kc += 64) {
      short8 a00 = *(const short8*)(pa0 + kc);
      short8 a01 = *(const short8*)(pa0 + kc + 32);
      short8 a10 = *(const short8*)(pa1 + kc);
      short8 a11 = *(const short8*)(pa1 + kc + 32);
      short8 b0[4], b1[4];
#pragma unroll
      for (int fc = 0; fc < 4; fc++) {
        b0[fc] = *(const short8*)(pb + (size_t)fc * 16 * K + kc);
        b1[fc] = *(const short8*)(pb + (size_t)fc * 16 * K + kc + 32);
      }
#pragma unroll
      for (int fc = 0; fc < 4; fc++) {
        acc[0][fc] = __builtin_amdgcn_mfma_f32_16x16x32_bf16(a00, b0[fc], acc[0][fc], 0, 0, 0);
        acc[1][fc] = __builtin_amdgcn_mfma_f32_16x16x32_bf16(a10, b0[fc], acc[1][fc], 0, 0, 0);
      }
#pragma unroll
      for (int fc = 0; fc < 4; fc++) {
        acc[0][fc] = __builtin_amdgcn_mfma_f32_16x16x32_bf16(a01, b1[fc], acc[0][fc], 0, 0, 0);
        acc[1][fc] = __builtin_amdgcn_mfma_f32_16x16x32_bf16(a11, b1[fc], acc[1][fc], 0, 0, 0);
      }
    }
    // stage bf16 subtile to LDS, XOR-swizzled: col' = col ^ (((row>>2)&3)<<4)
#pragma unroll
    for (int fc = 0; fc < 4; fc++) {
      int c = c0 + fc * 16 + lr;
      float bv = bias[c];
#pragma unroll
      for (int fr = 0; fr < 2; fr++) {
#pragma unroll
        for (int j = 0; j < 4; j++) {
          int row = fr * 16 + (lane >> 4) * 4 + j;
          int cs = c ^ (((row >> 2) & 3) << 4);
          lt[row][cs] = f2bf(acc[fr][fc][j] + bv);
        }
      }
    }
    __syncthreads();
    // coalesced write: 256 threads x 4 iters; each row written as contiguous 512B
#pragma unroll
    for (int it = 0; it < 4; it++) {
      int rl = (tid >> 5) + it * 8;
      int row = r + rl;
      if (row < NN) {
        int cs = cb ^ (((rl >> 2) & 3) << 4);
        short8 v = *(const short8*)&lt[rl][cs];
        *(short8*)(O + (size_t)row * 256 + cb) = v;
      }
    }
    __syncthreads();
  }
}

// ================= fused GATv2 edge phase (4-wide, branchless, 2-deep pipe) ====
__global__ __launch_bounds__(256) void gat_fused_kernel(const int* __restrict__ offsets,
                                                        const int* __restrict__ counts,
                                                        const int2* __restrict__ sedge,
                                                        const ushort* __restrict__ xl,
                                                        const ushort* __restrict__ xr,
                                                        const float* __restrict__ we,
                                                        const float* __restrict__ a06p,
                                                        const float* __restrict__ a04p,
                                                        const float* __restrict__ bias,
                                                        ushort* __restrict__ hb) {
  int w = threadIdx.x >> 6, lane = threadIdx.x & 63;
  int d = blockIdx.x * 4 + w;
  if (d >= NN) return;
  int off = offsets[d], cnt = counts[d];
  const int c4 = lane * 4;
  ushort4 xru = *(const ushort4*)(xr + (size_t)d * 256 + c4);
  const float4 xr4 = {bf2f(xru.x), bf2f(xru.y), bf2f(xru.z), bf2f(xru.w)};
  const float4 we4 = *(const float4*)(we + c4);
  const float4 a06 = *(const float4*)(a06p + c4);
  const float4 a04 = *(const float4*)(a04p + c4);
  float4 acc = {0.f, 0.f, 0.f, 0.f};
  float den = 0.f;
  const int2* pe = sedge + off;
  const char* xlc = (const char*)xl + (size_t)c4 * 2;  // sedge.x is byte offset
  // pipeline: e/xu = current iter, f/yu = next iter (all reads valid via pads)
  int2 e0 = pe[0], e1 = pe[1], e2 = pe[2], e3 = pe[3];
  ushort4 xu0 = *(const ushort4*)(xlc + (size_t)(unsigned)e0.x);
  ushort4 xu1 = *(const ushort4*)(xlc + (size_t)(unsigned)e1.x);
  ushort4 xu2 = *(const ushort4*)(xlc + (size_t)(unsigned)e2.x);
  ushort4 xu3 = *(const ushort4*)(xlc + (size_t)(unsigned)e3.x);
  int2 f0 = pe[4], f1 = pe[5], f2 = pe[6], f3 = pe[7];
  ushort4 yu0 = *(const ushort4*)(xlc + (size_t)(unsigned)f0.x);
  ushort4 yu1 = *(const ushort4*)(xlc + (size_t)(unsigned)f1.x);
  ushort4 yu2 = *(const ushort4*)(xlc + (size_t)(unsigned)f2.x);
  ushort4 yu3 = *(const ushort4*)(xlc + (size_t)(unsigned)f3.x);
#pragma unroll 2
  for (int i = 0; i < cnt; i += 4) {
    float ce0 = __int_as_float(e0.y), ce1 = __int_as_float(e1.y);
    float ce2 = __int_as_float(e2.y), ce3 = __int_as_float(e3.y);
    float4 x0 = {bf2f(xu0.x), bf2f(xu0.y), bf2f(xu0.z), bf2f(xu0.w)};
    float4 x1 = {bf2f(xu1.x), bf2f(xu1.y), bf2f(xu1.z), bf2f(xu1.w)};
    float4 x2 = {bf2f(xu2.x), bf2f(xu2.y), bf2f(xu2.z), bf2f(xu2.w)};
    float4 x3 = {bf2f(xu3.x), bf2f(xu3.y), bf2f(xu3.z), bf2f(xu3.w)};
    // rotate pipeline (renamed away under unroll) and prefetch slots i+8..i+11
    e0 = f0; e1 = f1; e2 = f2; e3 = f3;
    xu0 = yu0; xu1 = yu1; xu2 = yu2; xu3 = yu3;
    f0 = pe[i + 8]; f1 = pe[i + 9]; f2 = pe[i + 10]; f3 = pe[i + 11];
    yu0 = *(const ushort4*)(xlc + (size_t)(unsigned)f0.x);
    yu1 = *(const ushort4*)(xlc + (size_t)(unsigned)f1.x);
    yu2 = *(const ushort4*)(xlc + (size_t)(unsigned)f2.x);
    yu3 = *(const ushort4*)(xlc + (size_t)(unsigned)f3.x);
    float v0, v1, v2, v3;
    float p0, p1, p2, p3;
    v0 = x0.x + fmaf(ce0, we4.x, xr4.x);
    v1 = x0.y + fmaf(ce0, we4.y, xr4.y);
    v2 = x0.z + fmaf(ce0, we4.z, xr4.z);
    v3 = x0.w + fmaf(ce0, we4.w, xr4.w);
    p0 = fmaf(a06.x, v0, a04.x * fabsf(v0));
    p0 = fmaf(a06.y, v1, fmaf(a04.y, fabsf(v1), p0));
    p0 = fmaf(a06.z, v2, fmaf(a04.z, fabsf(v2), p0));
    p0 = fmaf(a06.w, v3, fmaf(a04.w, fabsf(v3), p0));
    v0 = x1.x + fmaf(ce1, we4.x, xr4.x);
    v1 = x1.y + fmaf(ce1, we4.y, xr4.y);
    v2 = x1.z + fmaf(ce1, we4.z, xr4.z);
    v3 = x1.w + fmaf(ce1, we4.w, xr4.w);
    p1 = fmaf(a06.x, v0, a04.x * fabsf(v0));
    p1 = fmaf(a06.y, v1, fmaf(a04.y, fabsf(v1), p1));
    p1 = fmaf(a06.z, v2, fmaf(a04.z, fabsf(v2), p1));
    p1 = fmaf(a06.w, v3, fmaf(a04.w, fabsf(v3), p1));
    v0 = x2.x + fmaf(ce2, we4.x, xr4.x);
    v1 = x2.y + fmaf(ce2, we4.y, xr4.y);
    v2 = x2.z + fmaf(ce2, we4.z, xr4.z);
    v3 = x2.w + fmaf(ce2, we4.w, xr4.w);
    p2 = fmaf(a06.x, v0, a04.x * fabsf(v0));
    p2 = fmaf(a06.y, v1, fmaf(a04.y, fabsf(v1), p2));
    p2 = fmaf(a06.z, v2, fmaf(a04.z, fabsf(v2), p2));
    p2 = fmaf(a06.w, v3, fmaf(a04.w, fabsf(v3), p2));
    v0 = x3.x + fmaf(ce3, we4.x, xr4.x);
    v1 = x3.y + fmaf(ce3, we4.y, xr4.y);
    v2 = x3.z + fmaf(ce3, we4.z, xr4.z);
    v3 = x3.w + fmaf(ce3, we4.w, xr4.w);
    p3 = fmaf(a06.x, v0, a04.x * fabsf(v0));
    p3 = fmaf(a06.y, v1, fmaf(a04.y, fabsf(v1), p3));
    p3 = fmaf(a06.z, v2, fmaf(a04.z, fabsf(v2), p3));
    p3 = fmaf(a06.w, v3, fmaf(a04.w, fabsf(v3), p3));
    p0 = row_reduce16(p0);
    p1 = row_reduce16(p1);
    p2 = row_reduce16(p2);
    p3 = row_reduce16(p3);
    float ex0 = exp2s(fminf(p0, 120.f));
    float ex1 = exp2s(fminf(p1, 120.f));
    float ex2 = exp2s(fminf(p2, 120.f));
    float ex3 = exp2s(fminf(p3, 120.f));
    ex1 = (i + 1 < cnt) ? ex1 : 0.f;  // wave-uniform tail masks
    ex2 = (i + 2 < cnt) ? ex2 : 0.f;
    ex3 = (i + 3 < cnt) ? ex3 : 0.f;
    den += (ex0 + ex1) + (ex2 + ex3);
    acc.x = fmaf(x0.x, ex0, fmaf(x1.x, ex1, fmaf(x2.x, ex2, fmaf(x3.x, ex3, acc.x))));
    acc.y = fmaf(x0.y, ex0, fmaf(x1.y, ex1, fmaf(x2.y, ex2, fmaf(x3.y, ex3, acc.y))));
    acc.z = fmaf(x0.z, ex0, fmaf(x1.z, ex1, fmaf(x2.z, ex2, fmaf(x3.z, ex3, acc.z))));
    acc.w = fmaf(x0.w, ex0, fmaf(x1.w, ex1, fmaf(x2.w, ex2, fmaf(x3.w, ex3, acc.w))));
  }
  const float4 b4 = *(const float4*)(bias + c4);
  float inv = 1.f / den;  // every node has a self-loop -> den > 0
  ushort4 o;
  o.x = f2bf(fmaxf(fmaf(acc.x, inv, b4.x), 0.f));
  o.y = f2bf(fmaxf(fmaf(acc.y, inv, b4.y), 0.f));
  o.z = f2bf(fmaxf(fmaf(acc.z, inv, b4.z), 0.f));
  o.w = f2bf(fmaxf(fmaf(acc.w, inv, b4.w), 0.f));
  *(ushort4*)(hb + (size_t)d * 256 + c4) = o;
}

// ---------- global mean pool (batch is sorted; run-length flush) ----------
__global__ __launch_bounds__(256) void pool_kernel(const ushort* __restrict__ h,
                                                   const int* __restrict__ batch,
                                                   float* __restrict__ sums,
                                                   float* __restrict__ cnts) {
  __shared__ int sb[128];
  int n0 = blockIdx.x * 128;
  int j = threadIdx.x;
  int count = min(128, NN - n0);
  if (count <= 0) return;
  for (int t = threadIdx.x; t < count; t += 256) sb[t] = batch[n0 + t];
  __syncthreads();
  float acc = 0.f;
  int run = 0;
  int cur = sb[0];
  for (int i = 0; i < count; ++i) {
    int b = sb[i];
    if (b != cur) {
      atomicAdd(&sums[(size_t)cur * 256 + j], acc);
      if (j == 0) atomicAdd(&cnts[cur], (float)run);
      acc = 0.f;
      run = 0;
      cur = b;
    }
    acc += bf2f(h[(size_t)(n0 + i) * 256 + j]);
    run++;
  }
  atomicAdd(&sums[(size_t)cur * 256 + j], acc);
  if (j == 0) atomicAdd(&cnts[cur], (float)run);
}

// ---------- post-MLP head: one block per graph ----------
__global__ __launch_bounds__(128) void head_kernel(const float* __restrict__ sums,
                                                   const float* __restrict__ cnts,
                                                   const float* __restrict__ p1_w,
                                                   const float* __restrict__ p1_b,
                                                   const float* __restrict__ ln_g,
                                                   const float* __restrict__ ln_b,
                                                   const float* __restrict__ p2_w,
                                                   const float* __restrict__ p2_b,
                                                   const float* __restrict__ hc_w,
                                                   const float* __restrict__ hc_b,
                                                   const float* __restrict__ hf_w,
                                                   const float* __restrict__ hf_b,
                                                   float* __restrict__ out) {
  int g = blockIdx.x;
  int j = threadIdx.x;  // 0..127
  __shared__ float sp[256], st[128], sz[64];
  float cnt = fmaxf(cnts[g], 1.0f);
  for (int t = j; t < 256; t += 128) sp[t] = sums[(size_t)g * 256 + t] / cnt;
  __syncthreads();
  float acc = p1_b[j];
  for (int k = 0; k < 256; k++) acc += sp[k] * p1_w[(size_t)k * 128 + j];
  st[j] = acc;
  __syncthreads();
  float mu = 0.f;
  for (int k = 0; k < 128; k++) mu += st[k];
  mu *= (1.f / 128.f);
  float var = 0.f;
  for (int k = 0; k < 128; k++) {
    float d = st[k] - mu;
    var += d * d;
  }
  var *= (1.f / 128.f);
  float tj = (acc - mu) * rsqrtf(var + 1e-5f) * ln_g[j] + ln_b[j];
  tj = fmaxf(tj, 0.f);
  __syncthreads();
  st[j] = tj;
  __syncthreads();
  if (j < 64) {
    float z = p2_b[j];
    for (int k = 0; k < 128; k++) z += st[k] * p2_w[(size_t)k * 64 + j];
    z = fmaxf(z, 0.f);
    sz[j] = z;
    out[500 + (size_t)g * 64 + j] = z;  // output 2: z [B,64]
  }
  __syncthreads();
  if (j == 0) {
    float c = hc_b[0];
    for (int k = 0; k < 64; k++) c += sz[k] * hc_w[k];
    out[g] = c;  // output 0: cooling [B]
  }
  if (j >= 1 && j < 10) {
    int f = j - 1;
    float v = hf_b[f];
    for (int k = 0; k < 64; k++) v += sz[k] * hf_w[(size_t)k * 9 + f];
    out[50 + (size_t)g * 9 + f] = v;  // output 1: fatigue [B,9]
  }
}

extern "C" void kernel_launch(void* const* d_in, const int* in_sizes, int n_in,
                              void* d_out, int out_size, void* d_ws, size_t ws_size,
                              hipStream_t stream) {
  const float* x = (const float*)d_in[0];
  const int* ei = (const int*)d_in[1];
  const float* ea = (const float*)d_in[2];
  const int* batch = (const int*)d_in[3];
  const float* enc_w = (const float*)d_in[4];
  const float* enc_b = (const float*)d_in[5];
  const float* g1_wl = (const float*)d_in[6];
  const float* g1_bl = (const float*)d_in[7];
  const float* g1_wr = (const float*)d_in[8];
  const float* g1_br = (const float*)d_in[9];
  const float* g1_we = (const float*)d_in[10];
  const float* g1_att = (const float*)d_in[11];
  const float* g1_bias = (const float*)d_in[12];
  const float* g2_wl = (const float*)d_in[13];
  const float* g2_bl = (const float*)d_in[14];
  const float* g2_wr = (const float*)d_in[15];
  const float* g2_br = (const float*)d_in[16];
  const float* g2_we = (const float*)d_in[17];
  const float* g2_att = (const float*)d_in[18];
  const float* g2_bias = (const float*)d_in[19];
  const float* p1_w = (const float*)d_in[20];
  const float* p1_b = (const float*)d_in[21];
  const float* ln_g = (const float*)d_in[22];
  const float* ln_b = (const float*)d_in[23];
  const float* p2_w = (const float*)d_in[24];
  const float* p2_b = (const float*)d_in[25];
  const float* hc_w = (const float*)d_in[26];
  const float* hc_b = (const float*)d_in[27];
  const float* hf_w = (const float*)d_in[28];
  const float* hf_b = (const float*)d_in[29];
  float* out = (float*)d_out;

  // ---- workspace layout ----
  ushort* xlb = (ushort*)d_ws;                    // N*256 bf16
  ushort* xrb = xlb + (size_t)NN * 256;           // N*256 bf16
  ushort* hb = xrb + (size_t)NN * 256;            // N*256 bf16
  ushort* h0b = hb + (size_t)NN * 256;            // N*64 bf16
  ushort* w1l = h0b + (size_t)NN * 64;            // 256*64 bf16 (transposed)
  ushort* w1r = w1l + 256 * 64;
  ushort* w2l = w1r + 256 * 64;                   // 256*256 bf16
  ushort* w2r = w2l + 256 * 256;
  int2* bucketed = (int2*)(w2r + 256 * 256);      // NBKT*CAP (pass-1 output)
  int2* sedge = bucketed + (size_t)NBKT * CAP;    // NBKT*CAP (sorted + pads)
  int* gcursor = (int*)(sedge + (size_t)NBKT * CAP);  // NBKT (zeroed below)
  int* counts = gcursor + NBKT;                   // NN
  int* offsets = counts + NN;                     // NN
  float* sums = (float*)(offsets + NN);           // B*256 (zeroed in setup)
  float* cnts = sums + (size_t)NB * 256;          // B    (zeroed in setup)
  float* partials = cnts + NB;                    // 256
  float* a06_1 = partials + 256;                  // 256
  float* a04_1 = a06_1 + 256;                     // 256
  float* a06_2 = a04_1 + 256;                     // 256
  float* a04_2 = a06_2 + 256;                     // 256

  // ---- gcursor = per-bucket fill counters (must be 0 before setup) ----
  hipMemsetAsync(gcursor, 0, NBKT * sizeof(int), stream);

  // ---- mega setup (bucket pass-1 + mean partials + encoder + wconv + att + zeros) ----
  setup_kernel<<<SETUP_GRID, 256, 0, stream>>>(
      x, enc_w, enc_b, h0b, ea, partials, ei, gcursor, bucketed,
      g1_wl, g1_wr, g2_wl, g2_wr, w1l, w1r, w2l, w2r,
      g1_att, g2_att, a06_1, a04_1, a06_2, a04_2, sums);

  // ---- pass 2: per-bucket sort (also patches self-loop ea with the mean) ----
  bucket_sort_kernel<<<NBKT, 256, 0, stream>>>(gcursor, partials, bucketed, sedge,
                                               offsets, counts);

  const dim3 gemmGrid(GEMM_GX, 2);
  const int nGatBlocks = (NN + 3) / 4;

  // ================= GAT layer 1 (K=64) =================
  dual_linear_pb<64><<<gemmGrid, 256, 0, stream>>>(h0b, w1l, w1r, g1_bl, g1_br, xlb, xrb);
  gat_fused_kernel<<<nGatBlocks, 256, 0, stream>>>(offsets, counts, sedge, xlb, xrb,
                                                   g1_we, a06_1, a04_1, g1_bias, hb);

  // ================= GAT layer 2 (K=256) =================
  dual_linear_pb<256><<<gemmGrid, 256, 0, stream>>>(hb, w2l, w2r, g2_bl, g2_br, xlb, xrb);
  gat_fused_kernel<<<nGatBlocks, 256, 0, stream>>>(offsets, counts, sedge, xlb, xrb,
                                                   g2_we, a06_2, a04_2, g2_bias, hb);

  // ================= pool + head =================
  pool_kernel<<<(NN + 127) / 128, 256, 0, stream>>>(hb, batch, sums, cnts);
  head_kernel<<<NB, 128, 0, stream>>>(sums, cnts, p1_w, p1_b, ln_g, ln_b, p2_w, p2_b,
                                      hc_w, hc_b, hf_w, hf_b, out);
}

// Round 21
// 242.882 us; speedup vs baseline: 1.0918x; 1.0353x over previous
//
#include <hip/hip_runtime.h>
#include <hip/hip_bf16.h>

#define NN 50000      // nodes
#define NE 500000     // edges (without self loops)
#define EP (NE + NN)  // edges with self loops
#define NB 50         // graphs
#define NEG 0.2f
#define NBKT 196        // ceil(NN/256) dst buckets (dst>>8)
#define CAP 3584        // per-bucket capacity (mean 2806 + ~14 sigma, incl 16 pad)
#define CHUNK 2048      // edges per bucket block
#define NBLK1 ((EP + CHUNK - 1) / CHUNK)  // 269 bucket blocks
#define NTILES 1563     // ceil(NN/32) row tiles for the GEMM
#define GEMM_GX 392     // grid.x for grid-stride GEMM (R16 optimum: ~4 tiles/block)
#define SELF_FLAG (1 << 24)  // marks self-loop edges awaiting mean-ea patch
#define SMEM_BYTES 31760     // max(gemm lt 17408, sort stage+hist+scn+cur+sw 31760)

// setup_kernel grid partition: bucket + mean first (critical path to sort)
#define MEAN_BLKS 256
#define ENC_BLKS 12500   // NN*64/256 exactly
#define WCONV_BLKS 640
#define ZERO_BLKS 51     // ceil((NB*256+NB)/256)
#define SETUP_GRID (NBLK1 + MEAN_BLKS + ENC_BLKS + WCONV_BLKS + 1 + ZERO_BLKS)

typedef __attribute__((ext_vector_type(8))) short short8;
typedef __attribute__((ext_vector_type(4))) float f32x4;

__device__ __forceinline__ ushort f2bf(float f) {
  unsigned u = __float_as_uint(f);
  unsigned r = (u + 0x7FFFu + ((u >> 16) & 1u)) >> 16;
  return (ushort)r;
}
__device__ __forceinline__ float bf2f(ushort b) {
  return __uint_as_float(((unsigned)b) << 16);
}

// hardware exp2 (v_exp_f32 is 2^x); s_nop covers the trans->VALU wait state
__device__ __forceinline__ float exp2s(float x) {
  float r;
  asm("v_exp_f32 %0, %1\ns_nop 0" : "=v"(r) : "v"(x));
  return r;
}

// all-lanes sum within each 16-lane row (head group), pure-VALU DPP
__device__ __forceinline__ float row_reduce16(float x) {
  x += __int_as_float(__builtin_amdgcn_mov_dpp(__float_as_int(x), 0xB1, 0xF, 0xF, true));
  x += __int_as_float(__builtin_amdgcn_mov_dpp(__float_as_int(x), 0x4E, 0xF, 0xF, true));
  x += __int_as_float(__builtin_amdgcn_mov_dpp(__float_as_int(x), 0x124, 0xF, 0xF, true));
  x += __int_as_float(__builtin_amdgcn_mov_dpp(__float_as_int(x), 0x128, 0xF, 0xF, true));
  return x;
}

// ================= mega setup: bucket pass-1 + mean-partials + encoder + wconv
// + att + zero(sums,cnts) — one launch; bucket blocks overlap encoder blocks.
__global__ __launch_bounds__(256) void setup_kernel(
    const float* __restrict__ x, const float* __restrict__ enc_w,
    const float* __restrict__ enc_b, ushort* __restrict__ h0,
    const float* __restrict__ ea, float* __restrict__ partials,
    const int* __restrict__ ei, int* __restrict__ gcursor,
    int2* __restrict__ bucketed,
    const float* __restrict__ g1_wl, const float* __restrict__ g1_wr,
    const float* __restrict__ g2_wl, const float* __restrict__ g2_wr,
    ushort* __restrict__ w1l, ushort* __restrict__ w1r,
    ushort* __restrict__ w2l, ushort* __restrict__ w2r,
    const float* __restrict__ att1, const float* __restrict__ att2,
    float* __restrict__ a06_1, float* __restrict__ a04_1,
    float* __restrict__ a06_2, float* __restrict__ a04_2,
    float* __restrict__ zero_region) {
  __shared__ float sw[4];
  __shared__ int hist[NBKT];
  __shared__ int lbase[NBKT];
  int b = blockIdx.x, t = threadIdx.x;
  if (b < NBLK1) {  // ---- bucket pass 1: LDS histogram + region reservation ----
    int e0 = b * CHUNK;
    for (int i = t; i < NBKT; i += 256) hist[i] = 0;
    __syncthreads();
    int packed[8], eab[8], bkt[8];
#pragma unroll
    for (int j = 0; j < 8; j++) {
      int e = e0 + j * 256 + t;
      bool valid = e < EP;
      int src, dst, fl = 0;
      float v = 0.f;
      if (e < NE) {
        src = ei[e];
        dst = ei[NE + e];
        v = ea[e];
      } else {
        int n = valid ? (e - NE) : 0;
        src = dst = n;
        fl = SELF_FLAG;  // ea patched to mean in the sort pass
      }
      bkt[j] = valid ? (dst >> 8) : -1;
      packed[j] = src | ((dst & 255) << 16) | fl;
      eab[j] = __float_as_int(v);
      if (valid) atomicAdd(&hist[dst >> 8], 1);
    }
    __syncthreads();
    for (int i = t; i < NBKT; i += 256)
      lbase[i] = hist[i] ? (i * CAP + atomicAdd(&gcursor[i], hist[i])) : 0;
    __syncthreads();
#pragma unroll
    for (int j = 0; j < 8; j++) {
      if (bkt[j] >= 0) {
        int pos = atomicAdd(&lbase[bkt[j]], 1);
        pos = min(pos, (bkt[j] + 1) * CAP - 1);  // overflow guard (never expected)
        bucketed[pos] = make_int2(packed[j], eab[j]);
      }
    }
    return;
  }
  b -= NBLK1;
  if (b < MEAN_BLKS) {  // ---- edge_attr mean partial sums (no atomics) ----
    int idx = b * 256 + t;
    float v = 0.f;
    for (int i = idx; i < NE; i += 65536) v += ea[i];
    for (int off = 1; off < 64; off <<= 1) v += __shfl_xor(v, off, 64);
    if ((t & 63) == 0) sw[t >> 6] = v;
    __syncthreads();
    if (t == 0) partials[b] = sw[0] + sw[1] + sw[2] + sw[3];
    return;
  }
  b -= MEAN_BLKS;
  if (b < ENC_BLKS) {  // ---- encoder: h0 = relu(x @ enc_w + enc_b), bf16 ----
    int i = b * 256 + t;  // exactly NN*64
    int n = i >> 6, j = i & 63;
    float acc = enc_b[j];
#pragma unroll
    for (int k = 0; k < 8; k++) acc += x[n * 8 + k] * enc_w[k * 64 + j];
    h0[i] = f2bf(fmaxf(acc, 0.f));
    return;
  }
  b -= ENC_BLKS;
  if (b < WCONV_BLKS) {  // ---- weight converts f32 [K][256] -> bf16 [256][K] ----
    if (b < 128) {
      int sec = b >> 6;
      const float* W = sec ? g1_wr : g1_wl;
      ushort* Wt = sec ? w1r : w1l;
      int i = (b & 63) * 256 + t;
      int n = i >> 6, k = i & 63;
      Wt[i] = f2bf(W[(size_t)k * 256 + n]);
    } else {
      int bb = b - 128;
      int sec = bb >> 8;
      const float* W = sec ? g2_wr : g2_wl;
      ushort* Wt = sec ? w2r : w2l;
      int i = (bb & 255) * 256 + t;
      int n = i >> 8, k = i & 255;
      Wt[i] = f2bf(W[(size_t)k * 256 + n]);
    }
    return;
  }
  b -= WCONV_BLKS;
  if (b == 0) {  // ---- att pre-scale ----
    const float L2E = 1.44269504f;
    float v1 = att1[t], v2 = att2[t];
    a06_1[t] = 0.6f * L2E * v1;
    a04_1[t] = 0.4f * L2E * v1;
    a06_2[t] = 0.6f * L2E * v2;
    a04_2[t] = 0.4f * L2E * v2;
    return;
  }
  b -= 1;
  {  // ---- zero sums+cnts (contiguous region of NB*256+NB floats) ----
    int i = b * 256 + t;
    if (i < NB * 256 + NB) zero_region[i] = 0.f;
  }
}

// ---------- dual linear via MFMA (R16 optimum) + optional fused bucket-sort ----
// WITH_SORT: blocks with x >= GEMM_GX (y==0) run the per-bucket counting sort
// concurrently with the GEMM (the two have no mutual dependency; both need
// only setup_kernel's outputs). LDS is a shared arena (overlaid layouts).
template <int K, bool WITH_SORT>
__global__ __launch_bounds__(256) void dual_linear_pb(
    const ushort* __restrict__ A, const ushort* __restrict__ Wl,
    const ushort* __restrict__ Wr, const float* __restrict__ bl,
    const float* __restrict__ br, ushort* __restrict__ xl,
    ushort* __restrict__ xr,
    const int* __restrict__ gcursor, const float* __restrict__ partials,
    const int2* __restrict__ bucketed, int2* __restrict__ sedge,
    int* __restrict__ offsets, int* __restrict__ counts) {
  __shared__ __align__(16) char smem[SMEM_BYTES];
  int t = threadIdx.x;
  if (WITH_SORT && blockIdx.x >= GEMM_GX) {
    if (blockIdx.y != 0) return;
    // ======== bucket sort pass 2 (all-LDS), patches self-loop ea ========
    int2* stage = (int2*)smem;                     // CAP
    int* hist = (int*)(smem + CAP * 8);            // 256
    int* scn = hist + 256;                         // 256
    int* cur = scn + 256;                          // 256
    float* sw = (float*)(cur + 256);               // 4
    int b = blockIdx.x - GEMM_GX;
    float pv = partials[t];
    for (int off = 1; off < 64; off <<= 1) pv += __shfl_xor(pv, off, 64);
    if ((t & 63) == 0) sw[t >> 6] = pv;
    hist[t] = 0;
    __syncthreads();
    int meanb = __float_as_int((sw[0] + sw[1] + sw[2] + sw[3]) * (1.0f / NE));
    int base = b * CAP;
    int nb = min(gcursor[b], CAP - 16);
    for (int i = t; i < nb; i += 256) {
      int2 s = bucketed[base + i];
      if (s.x & SELF_FLAG) s.y = meanb;  // patch self-loop ea to mean
      stage[i] = s;
    }
    __syncthreads();
    if (t < 16) {  // pad entries (masked in gat; always-valid prefetch reads)
      int2 pv2 = make_int2((stage[0].x & 0xFFFF) << 9, stage[0].y);
      sedge[base + nb + t] = pv2;
    }
    for (int i = t; i < nb; i += 256) atomicAdd(&hist[(stage[i].x >> 16) & 255], 1);
    __syncthreads();
    int v = hist[t];
    scn[t] = v;
    __syncthreads();
    for (int off = 1; off < 256; off <<= 1) {
      int add = (t >= off) ? scn[t - off] : 0;
      __syncthreads();
      scn[t] += add;
      __syncthreads();
    }
    int excl = scn[t] - v;
    cur[t] = excl;
    __syncthreads();
    for (int i = t; i < nb; i += 256) {
      int dl = (stage[i].x >> 16) & 255;
      int p = atomicAdd(&cur[dl], 1);
      sedge[base + p] = make_int2((stage[i].x & 0xFFFF) << 9, stage[i].y);
    }
    int d = b * 256 + t;
    if (d < NN) {
      offsets[d] = base + excl;
      counts[d] = v;
    }
    return;
  }
  // ======== GEMM: 32-row tiles, K-chunked registers, grid-stride ========
  ushort(*lt)[272] = reinterpret_cast<ushort(*)[272]>(smem);
  int wave = t >> 6, lane = t & 63;
  int lr = lane & 15;        // row-in-frag (A) / col-in-frag (B/D)
  int kb = (lane >> 4) * 8;  // k-base within 32-wide k-step
  const ushort* W = blockIdx.y ? Wr : Wl;
  const float* bias = blockIdx.y ? br : bl;
  ushort* O = blockIdx.y ? xr : xl;
  const int c0 = wave * 64;
  const ushort* pb = W + (size_t)(c0 + lr) * K + kb;
  int cb = (t & 31) * 8;  // col base for the coalesced write phase

  for (int tt = blockIdx.x; tt < NTILES; tt += GEMM_GX) {
    int r = tt * 32;
    int ra0 = min(r + lr, NN - 1);
    int ra1 = min(r + 16 + lr, NN - 1);
    const ushort* pa0 = A + (size_t)ra0 * K + kb;
    const ushort* pa1 = A + (size_t)ra1 * K + kb;
    f32x4 acc[2][4];
#pragma unroll
    for (int fr = 0; fr < 2; fr++)
#pragma unroll
      for (int fc = 0; fc < 4; fc++) acc[fr][fc] = (f32x4){0.f, 0.f, 0.f, 0.f};
#pragma unroll
    for (int kc = 0; kc < K; kc += 64) {
      short8 a00 = *(const short8*)(pa0 + kc);
      short8 a01 = *(const short8*)(pa0 + kc + 32);
      short8 a10 = *(const short8*)(pa1 + kc);
      short8 a11 = *(const short8*)(pa1 + kc + 32);
      short8 b0[4], b1[4];
#pragma unroll
      for (int fc = 0; fc < 4; fc++) {
        b0[fc] = *(const short8*)(pb + (size_t)fc * 16 * K + kc);
        b1[fc] = *(const short8*)(pb + (size_t)fc * 16 * K + kc + 32);
      }
#pragma unroll
      for (int fc = 0; fc < 4; fc++) {
        acc[0][fc] = __builtin_amdgcn_mfma_f32_16x16x32_bf16(a00, b0[fc], acc[0][fc], 0, 0, 0);
        acc[1][fc] = __builtin_amdgcn_mfma_f32_16x16x32_bf16(a10, b0[fc], acc[1][fc], 0, 0, 0);
      }
#pragma unroll
      for (int fc = 0; fc < 4; fc++) {
        acc[0][fc] = __builtin_amdgcn_mfma_f32_16x16x32_bf16(a01, b1[fc], acc[0][fc], 0, 0, 0);
        acc[1][fc] = __builtin_amdgcn_mfma_f32_16x16x32_bf16(a11, b1[fc], acc[1][fc], 0, 0, 0);
      }
    }
    // stage bf16 subtile to LDS, XOR-swizzled: col' = col ^ (((row>>2)&3)<<4)
#pragma unroll
    for (int fc = 0; fc < 4; fc++) {
      int c = c0 + fc * 16 + lr;
      float bv = bias[c];
#pragma unroll
      for (int fr = 0; fr < 2; fr++) {
#pragma unroll
        for (int j = 0; j < 4; j++) {
          int row = fr * 16 + (lane >> 4) * 4 + j;
          int cs = c ^ (((row >> 2) & 3) << 4);
          lt[row][cs] = f2bf(acc[fr][fc][j] + bv);
        }
      }
    }
    __syncthreads();
    // coalesced write: 256 threads x 4 iters; each row written as contiguous 512B
#pragma unroll
    for (int it = 0; it < 4; it++) {
      int rl = (t >> 5) + it * 8;
      int row = r + rl;
      if (row < NN) {
        int cs = cb ^ (((rl >> 2) & 3) << 4);
        short8 v = *(const short8*)&lt[rl][cs];
        *(short8*)(O + (size_t)row * 256 + cb) = v;
      }
    }
    __syncthreads();
  }
}

// ================= fused GATv2 edge phase (4-wide, branchless, 2-deep pipe) ====
__global__ __launch_bounds__(256) void gat_fused_kernel(const int* __restrict__ offsets,
                                                        const int* __restrict__ counts,
                                                        const int2* __restrict__ sedge,
                                                        const ushort* __restrict__ xl,
                                                        const ushort* __restrict__ xr,
                                                        const float* __restrict__ we,
                                                        const float* __restrict__ a06p,
                                                        const float* __restrict__ a04p,
                                                        const float* __restrict__ bias,
                                                        ushort* __restrict__ hb) {
  int w = threadIdx.x >> 6, lane = threadIdx.x & 63;
  int d = blockIdx.x * 4 + w;
  if (d >= NN) return;
  int off = offsets[d], cnt = counts[d];
  const int c4 = lane * 4;
  ushort4 xru = *(const ushort4*)(xr + (size_t)d * 256 + c4);
  const float4 xr4 = {bf2f(xru.x), bf2f(xru.y), bf2f(xru.z), bf2f(xru.w)};
  const float4 we4 = *(const float4*)(we + c4);
  const float4 a06 = *(const float4*)(a06p + c4);
  const float4 a04 = *(const float4*)(a04p + c4);
  float4 acc = {0.f, 0.f, 0.f, 0.f};
  float den = 0.f;
  const int2* pe = sedge + off;
  const char* xlc = (const char*)xl + (size_t)c4 * 2;  // sedge.x is byte offset
  int2 e0 = pe[0], e1 = pe[1], e2 = pe[2], e3 = pe[3];
  ushort4 xu0 = *(const ushort4*)(xlc + (size_t)(unsigned)e0.x);
  ushort4 xu1 = *(const ushort4*)(xlc + (size_t)(unsigned)e1.x);
  ushort4 xu2 = *(const ushort4*)(xlc + (size_t)(unsigned)e2.x);
  ushort4 xu3 = *(const ushort4*)(xlc + (size_t)(unsigned)e3.x);
  int2 f0 = pe[4], f1 = pe[5], f2 = pe[6], f3 = pe[7];
  ushort4 yu0 = *(const ushort4*)(xlc + (size_t)(unsigned)f0.x);
  ushort4 yu1 = *(const ushort4*)(xlc + (size_t)(unsigned)f1.x);
  ushort4 yu2 = *(const ushort4*)(xlc + (size_t)(unsigned)f2.x);
  ushort4 yu3 = *(const ushort4*)(xlc + (size_t)(unsigned)f3.x);
#pragma unroll 2
  for (int i = 0; i < cnt; i += 4) {
    float ce0 = __int_as_float(e0.y), ce1 = __int_as_float(e1.y);
    float ce2 = __int_as_float(e2.y), ce3 = __int_as_float(e3.y);
    float4 x0 = {bf2f(xu0.x), bf2f(xu0.y), bf2f(xu0.z), bf2f(xu0.w)};
    float4 x1 = {bf2f(xu1.x), bf2f(xu1.y), bf2f(xu1.z), bf2f(xu1.w)};
    float4 x2 = {bf2f(xu2.x), bf2f(xu2.y), bf2f(xu2.z), bf2f(xu2.w)};
    float4 x3 = {bf2f(xu3.x), bf2f(xu3.y), bf2f(xu3.z), bf2f(xu3.w)};
    e0 = f0; e1 = f1; e2 = f2; e3 = f3;
    xu0 = yu0; xu1 = yu1; xu2 = yu2; xu3 = yu3;
    f0 = pe[i + 8]; f1 = pe[i + 9]; f2 = pe[i + 10]; f3 = pe[i + 11];
    yu0 = *(const ushort4*)(xlc + (size_t)(unsigned)f0.x);
    yu1 = *(const ushort4*)(xlc + (size_t)(unsigned)f1.x);
    yu2 = *(const ushort4*)(xlc + (size_t)(unsigned)f2.x);
    yu3 = *(const ushort4*)(xlc + (size_t)(unsigned)f3.x);
    float v0, v1, v2, v3;
    float p0, p1, p2, p3;
    v0 = x0.x + fmaf(ce0, we4.x, xr4.x);
    v1 = x0.y + fmaf(ce0, we4.y, xr4.y);
    v2 = x0.z + fmaf(ce0, we4.z, xr4.z);
    v3 = x0.w + fmaf(ce0, we4.w, xr4.w);
    p0 = fmaf(a06.x, v0, a04.x * fabsf(v0));
    p0 = fmaf(a06.y, v1, fmaf(a04.y, fabsf(v1), p0));
    p0 = fmaf(a06.z, v2, fmaf(a04.z, fabsf(v2), p0));
    p0 = fmaf(a06.w, v3, fmaf(a04.w, fabsf(v3), p0));
    v0 = x1.x + fmaf(ce1, we4.x, xr4.x);
    v1 = x1.y + fmaf(ce1, we4.y, xr4.y);
    v2 = x1.z + fmaf(ce1, we4.z, xr4.z);
    v3 = x1.w + fmaf(ce1, we4.w, xr4.w);
    p1 = fmaf(a06.x, v0, a04.x * fabsf(v0));
    p1 = fmaf(a06.y, v1, fmaf(a04.y, fabsf(v1), p1));
    p1 = fmaf(a06.z, v2, fmaf(a04.z, fabsf(v2), p1));
    p1 = fmaf(a06.w, v3, fmaf(a04.w, fabsf(v3), p1));
    v0 = x2.x + fmaf(ce2, we4.x, xr4.x);
    v1 = x2.y + fmaf(ce2, we4.y, xr4.y);
    v2 = x2.z + fmaf(ce2, we4.z, xr4.z);
    v3 = x2.w + fmaf(ce2, we4.w, xr4.w);
    p2 = fmaf(a06.x, v0, a04.x * fabsf(v0));
    p2 = fmaf(a06.y, v1, fmaf(a04.y, fabsf(v1), p2));
    p2 = fmaf(a06.z, v2, fmaf(a04.z, fabsf(v2), p2));
    p2 = fmaf(a06.w, v3, fmaf(a04.w, fabsf(v3), p2));
    v0 = x3.x + fmaf(ce3, we4.x, xr4.x);
    v1 = x3.y + fmaf(ce3, we4.y, xr4.y);
    v2 = x3.z + fmaf(ce3, we4.z, xr4.z);
    v3 = x3.w + fmaf(ce3, we4.w, xr4.w);
    p3 = fmaf(a06.x, v0, a04.x * fabsf(v0));
    p3 = fmaf(a06.y, v1, fmaf(a04.y, fabsf(v1), p3));
    p3 = fmaf(a06.z, v2, fmaf(a04.z, fabsf(v2), p3));
    p3 = fmaf(a06.w, v3, fmaf(a04.w, fabsf(v3), p3));
    p0 = row_reduce16(p0);
    p1 = row_reduce16(p1);
    p2 = row_reduce16(p2);
    p3 = row_reduce16(p3);
    float ex0 = exp2s(fminf(p0, 120.f));
    float ex1 = exp2s(fminf(p1, 120.f));
    float ex2 = exp2s(fminf(p2, 120.f));
    float ex3 = exp2s(fminf(p3, 120.f));
    ex1 = (i + 1 < cnt) ? ex1 : 0.f;  // wave-uniform tail masks
    ex2 = (i + 2 < cnt) ? ex2 : 0.f;
    ex3 = (i + 3 < cnt) ? ex3 : 0.f;
    den += (ex0 + ex1) + (ex2 + ex3);
    acc.x = fmaf(x0.x, ex0, fmaf(x1.x, ex1, fmaf(x2.x, ex2, fmaf(x3.x, ex3, acc.x))));
    acc.y = fmaf(x0.y, ex0, fmaf(x1.y, ex1, fmaf(x2.y, ex2, fmaf(x3.y, ex3, acc.y))));
    acc.z = fmaf(x0.z, ex0, fmaf(x1.z, ex1, fmaf(x2.z, ex2, fmaf(x3.z, ex3, acc.z))));
    acc.w = fmaf(x0.w, ex0, fmaf(x1.w, ex1, fmaf(x2.w, ex2, fmaf(x3.w, ex3, acc.w))));
  }
  const float4 b4 = *(const float4*)(bias + c4);
  float inv = 1.f / den;  // every node has a self-loop -> den > 0
  ushort4 o;
  o.x = f2bf(fmaxf(fmaf(acc.x, inv, b4.x), 0.f));
  o.y = f2bf(fmaxf(fmaf(acc.y, inv, b4.y), 0.f));
  o.z = f2bf(fmaxf(fmaf(acc.z, inv, b4.z), 0.f));
  o.w = f2bf(fmaxf(fmaf(acc.w, inv, b4.w), 0.f));
  *(ushort4*)(hb + (size_t)d * 256 + c4) = o;
}

// ---------- global mean pool (batch is sorted; run-length flush) ----------
__global__ __launch_bounds__(256) void pool_kernel(const ushort* __restrict__ h,
                                                   const int* __restrict__ batch,
                                                   float* __restrict__ sums,
                                                   float* __restrict__ cnts) {
  __shared__ int sb[128];
  int n0 = blockIdx.x * 128;
  int j = threadIdx.x;
  int count = min(128, NN - n0);
  if (count <= 0) return;
  for (int t = threadIdx.x; t < count; t += 256) sb[t] = batch[n0 + t];
  __syncthreads();
  float acc = 0.f;
  int run = 0;
  int cur = sb[0];
  for (int i = 0; i < count; ++i) {
    int b = sb[i];
    if (b != cur) {
      atomicAdd(&sums[(size_t)cur * 256 + j], acc);
      if (j == 0) atomicAdd(&cnts[cur], (float)run);
      acc = 0.f;
      run = 0;
      cur = b;
    }
    acc += bf2f(h[(size_t)(n0 + i) * 256 + j]);
    run++;
  }
  atomicAdd(&sums[(size_t)cur * 256 + j], acc);
  if (j == 0) atomicAdd(&cnts[cur], (float)run);
}

// ---------- post-MLP head: one block per graph ----------
__global__ __launch_bounds__(128) void head_kernel(const float* __restrict__ sums,
                                                   const float* __restrict__ cnts,
                                                   const float* __restrict__ p1_w,
                                                   const float* __restrict__ p1_b,
                                                   const float* __restrict__ ln_g,
                                                   const float* __restrict__ ln_b,
                                                   const float* __restrict__ p2_w,
                                                   const float* __restrict__ p2_b,
                                                   const float* __restrict__ hc_w,
                                                   const float* __restrict__ hc_b,
                                                   const float* __restrict__ hf_w,
                                                   const float* __restrict__ hf_b,
                                                   float* __restrict__ out) {
  int g = blockIdx.x;
  int j = threadIdx.x;  // 0..127
  __shared__ float sp[256], st[128], sz[64];
  float cnt = fmaxf(cnts[g], 1.0f);
  for (int t = j; t < 256; t += 128) sp[t] = sums[(size_t)g * 256 + t] / cnt;
  __syncthreads();
  float acc = p1_b[j];
  for (int k = 0; k < 256; k++) acc += sp[k] * p1_w[(size_t)k * 128 + j];
  st[j] = acc;
  __syncthreads();
  float mu = 0.f;
  for (int k = 0; k < 128; k++) mu += st[k];
  mu *= (1.f / 128.f);
  float var = 0.f;
  for (int k = 0; k < 128; k++) {
    float d = st[k] - mu;
    var += d * d;
  }
  var *= (1.f / 128.f);
  float tj = (acc - mu) * rsqrtf(var + 1e-5f) * ln_g[j] + ln_b[j];
  tj = fmaxf(tj, 0.f);
  __syncthreads();
  st[j] = tj;
  __syncthreads();
  if (j < 64) {
    float z = p2_b[j];
    for (int k = 0; k < 128; k++) z += st[k] * p2_w[(size_t)k * 64 + j];
    z = fmaxf(z, 0.f);
    sz[j] = z;
    out[500 + (size_t)g * 64 + j] = z;  // output 2: z [B,64]
  }
  __syncthreads();
  if (j == 0) {
    float c = hc_b[0];
    for (int k = 0; k < 64; k++) c += sz[k] * hc_w[k];
    out[g] = c;  // output 0: cooling [B]
  }
  if (j >= 1 && j < 10) {
    int f = j - 1;
    float v = hf_b[f];
    for (int k = 0; k < 64; k++) v += sz[k] * hf_w[(size_t)k * 9 + f];
    out[50 + (size_t)g * 9 + f] = v;  // output 1: fatigue [B,9]
  }
}

extern "C" void kernel_launch(void* const* d_in, const int* in_sizes, int n_in,
                              void* d_out, int out_size, void* d_ws, size_t ws_size,
                              hipStream_t stream) {
  const float* x = (const float*)d_in[0];
  const int* ei = (const int*)d_in[1];
  const float* ea = (const float*)d_in[2];
  const int* batch = (const int*)d_in[3];
  const float* enc_w = (const float*)d_in[4];
  const float* enc_b = (const float*)d_in[5];
  const float* g1_wl = (const float*)d_in[6];
  const float* g1_bl = (const float*)d_in[7];
  const float* g1_wr = (const float*)d_in[8];
  const float* g1_br = (const float*)d_in[9];
  const float* g1_we = (const float*)d_in[10];
  const float* g1_att = (const float*)d_in[11];
  const float* g1_bias = (const float*)d_in[12];
  const float* g2_wl = (const float*)d_in[13];
  const float* g2_bl = (const float*)d_in[14];
  const float* g2_wr = (const float*)d_in[15];
  const float* g2_br = (const float*)d_in[16];
  const float* g2_we = (const float*)d_in[17];
  const float* g2_att = (const float*)d_in[18];
  const float* g2_bias = (const float*)d_in[19];
  const float* p1_w = (const float*)d_in[20];
  const float* p1_b = (const float*)d_in[21];
  const float* ln_g = (const float*)d_in[22];
  const float* ln_b = (const float*)d_in[23];
  const float* p2_w = (const float*)d_in[24];
  const float* p2_b = (const float*)d_in[25];
  const float* hc_w = (const float*)d_in[26];
  const float* hc_b = (const float*)d_in[27];
  const float* hf_w = (const float*)d_in[28];
  const float* hf_b = (const float*)d_in[29];
  float* out = (float*)d_out;

  // ---- workspace layout ----
  ushort* xlb = (ushort*)d_ws;                    // N*256 bf16
  ushort* xrb = xlb + (size_t)NN * 256;           // N*256 bf16
  ushort* hb = xrb + (size_t)NN * 256;            // N*256 bf16
  ushort* h0b = hb + (size_t)NN * 256;            // N*64 bf16
  ushort* w1l = h0b + (size_t)NN * 64;            // 256*64 bf16 (transposed)
  ushort* w1r = w1l + 256 * 64;
  ushort* w2l = w1r + 256 * 64;                   // 256*256 bf16
  ushort* w2r = w2l + 256 * 256;
  int2* bucketed = (int2*)(w2r + 256 * 256);      // NBKT*CAP (pass-1 output)
  int2* sedge = bucketed + (size_t)NBKT * CAP;    // NBKT*CAP (sorted + pads)
  int* gcursor = (int*)(sedge + (size_t)NBKT * CAP);  // NBKT (zeroed below)
  int* counts = gcursor + NBKT;                   // NN
  int* offsets = counts + NN;                     // NN
  float* sums = (float*)(offsets + NN);           // B*256 (zeroed in setup)
  float* cnts = sums + (size_t)NB * 256;          // B    (zeroed in setup)
  float* partials = cnts + NB;                    // 256
  float* a06_1 = partials + 256;                  // 256
  float* a04_1 = a06_1 + 256;                     // 256
  float* a06_2 = a04_1 + 256;                     // 256
  float* a04_2 = a06_2 + 256;                     // 256

  // ---- gcursor = per-bucket fill counters (must be 0 before setup) ----
  hipMemsetAsync(gcursor, 0, NBKT * sizeof(int), stream);

  // ---- mega setup (bucket pass-1 + mean partials + encoder + wconv + att + zeros) ----
  setup_kernel<<<SETUP_GRID, 256, 0, stream>>>(
      x, enc_w, enc_b, h0b, ea, partials, ei, gcursor, bucketed,
      g1_wl, g1_wr, g2_wl, g2_wr, w1l, w1r, w2l, w2r,
      g1_att, g2_att, a06_1, a04_1, a06_2, a04_2, sums);

  const int nGatBlocks = (NN + 3) / 4;

  // ========== GAT layer 1 (K=64) — GEMM fused with bucket-sort pass 2 ==========
  dim3 g64(GEMM_GX + NBKT, 2);
  dual_linear_pb<64, true><<<g64, 256, 0, stream>>>(
      h0b, w1l, w1r, g1_bl, g1_br, xlb, xrb,
      gcursor, partials, bucketed, sedge, offsets, counts);
  gat_fused_kernel<<<nGatBlocks, 256, 0, stream>>>(offsets, counts, sedge, xlb, xrb,
                                                   g1_we, a06_1, a04_1, g1_bias, hb);

  // ================= GAT layer 2 (K=256) =================
  dim3 g256(GEMM_GX, 2);
  dual_linear_pb<256, false><<<g256, 256, 0, stream>>>(
      hb, w2l, w2r, g2_bl, g2_br, xlb, xrb,
      gcursor, partials, bucketed, sedge, offsets, counts);
  gat_fused_kernel<<<nGatBlocks, 256, 0, stream>>>(offsets, counts, sedge, xlb, xrb,
                                                   g2_we, a06_2, a04_2, g2_bias, hb);

  // ================= pool + head =================
  pool_kernel<<<(NN + 127) / 128, 256, 0, stream>>>(hb, batch, sums, cnts);
  head_kernel<<<NB, 128, 0, stream>>>(sums, cnts, p1_w, p1_b, ln_g, ln_b, p2_w, p2_b,
                                      hc_w, hc_b, hf_w, hf_b, out);
}

// Round 22
// 225.341 us; speedup vs baseline: 1.1768x; 1.0778x over previous
//
#include <hip/hip_runtime.h>
#include <hip/hip_bf16.h>

#define NN 50000      // nodes
#define NE 500000     // edges (without self loops)
#define EP (NE + NN)  // edges with self loops
#define NB 50         // graphs
#define NEG 0.2f
#define NBKT 196        // ceil(NN/256) dst buckets (dst>>8)
#define CAP 3584        // per-bucket capacity (mean 2806 + ~14 sigma, incl 16 pad)
#define CHUNK 2048      // edges per bucket block
#define NBLK1 ((EP + CHUNK - 1) / CHUNK)  // 269 bucket blocks
#define NTILES 1563     // ceil(NN/32) row tiles for the GEMM
#define GEMM_GX 392     // grid.x for grid-stride GEMM (~4 tiles/block)
#define SELF_FLAG (1 << 24)  // marks self-loop edges awaiting mean-ea patch
#define SORT_SMEM 31760      // sort arena: stage(28672)+hist/scn/cur(3072)+sw(16)

// setup_kernel grid partition: bucket + mean first (critical path to sort)
#define MEAN_BLKS 256
#define ENC_BLKS 12500   // NN*64/256 exactly
#define WCONV_BLKS 640
#define ZERO_BLKS 51     // ceil((NB*256+NB)/256)
#define SETUP_GRID (NBLK1 + MEAN_BLKS + ENC_BLKS + WCONV_BLKS + 1 + ZERO_BLKS)

typedef __attribute__((ext_vector_type(8))) short short8;
typedef __attribute__((ext_vector_type(4))) float f32x4;

__device__ __forceinline__ ushort f2bf(float f) {
  unsigned u = __float_as_uint(f);
  unsigned r = (u + 0x7FFFu + ((u >> 16) & 1u)) >> 16;
  return (ushort)r;
}
__device__ __forceinline__ float bf2f(ushort b) {
  return __uint_as_float(((unsigned)b) << 16);
}

// hardware exp2 (v_exp_f32 is 2^x); s_nop covers the trans->VALU wait state
__device__ __forceinline__ float exp2s(float x) {
  float r;
  asm("v_exp_f32 %0, %1\ns_nop 0" : "=v"(r) : "v"(x));
  return r;
}

// all-lanes sum within each 16-lane row (head group), pure-VALU DPP
__device__ __forceinline__ float row_reduce16(float x) {
  x += __int_as_float(__builtin_amdgcn_mov_dpp(__float_as_int(x), 0xB1, 0xF, 0xF, true));
  x += __int_as_float(__builtin_amdgcn_mov_dpp(__float_as_int(x), 0x4E, 0xF, 0xF, true));
  x += __int_as_float(__builtin_amdgcn_mov_dpp(__float_as_int(x), 0x124, 0xF, 0xF, true));
  x += __int_as_float(__builtin_amdgcn_mov_dpp(__float_as_int(x), 0x128, 0xF, 0xF, true));
  return x;
}

// ================= mega setup: bucket pass-1 + mean-partials + encoder + wconv
// + att + zero(sums,cnts) — one launch; bucket blocks overlap encoder blocks.
__global__ __launch_bounds__(256) void setup_kernel(
    const float* __restrict__ x, const float* __restrict__ enc_w,
    const float* __restrict__ enc_b, ushort* __restrict__ h0,
    const float* __restrict__ ea, float* __restrict__ partials,
    const int* __restrict__ ei, int* __restrict__ gcursor,
    int2* __restrict__ bucketed,
    const float* __restrict__ g1_wl, const float* __restrict__ g1_wr,
    const float* __restrict__ g2_wl, const float* __restrict__ g2_wr,
    ushort* __restrict__ w1l, ushort* __restrict__ w1r,
    ushort* __restrict__ w2l, ushort* __restrict__ w2r,
    const float* __restrict__ att1, const float* __restrict__ att2,
    float* __restrict__ a06_1, float* __restrict__ a04_1,
    float* __restrict__ a06_2, float* __restrict__ a04_2,
    float* __restrict__ zero_region) {
  __shared__ float sw[4];
  __shared__ int hist[NBKT];
  __shared__ int lbase[NBKT];
  int b = blockIdx.x, t = threadIdx.x;
  if (b < NBLK1) {  // ---- bucket pass 1: LDS histogram + region reservation ----
    int e0 = b * CHUNK;
    for (int i = t; i < NBKT; i += 256) hist[i] = 0;
    __syncthreads();
    int packed[8], eab[8], bkt[8];
#pragma unroll
    for (int j = 0; j < 8; j++) {
      int e = e0 + j * 256 + t;
      bool valid = e < EP;
      int src, dst, fl = 0;
      float v = 0.f;
      if (e < NE) {
        src = ei[e];
        dst = ei[NE + e];
        v = ea[e];
      } else {
        int n = valid ? (e - NE) : 0;
        src = dst = n;
        fl = SELF_FLAG;  // ea patched to mean in the sort pass
      }
      bkt[j] = valid ? (dst >> 8) : -1;
      packed[j] = src | ((dst & 255) << 16) | fl;
      eab[j] = __float_as_int(v);
      if (valid) atomicAdd(&hist[dst >> 8], 1);
    }
    __syncthreads();
    for (int i = t; i < NBKT; i += 256)
      lbase[i] = hist[i] ? (i * CAP + atomicAdd(&gcursor[i], hist[i])) : 0;
    __syncthreads();
#pragma unroll
    for (int j = 0; j < 8; j++) {
      if (bkt[j] >= 0) {
        int pos = atomicAdd(&lbase[bkt[j]], 1);
        pos = min(pos, (bkt[j] + 1) * CAP - 1);  // overflow guard (never expected)
        bucketed[pos] = make_int2(packed[j], eab[j]);
      }
    }
    return;
  }
  b -= NBLK1;
  if (b < MEAN_BLKS) {  // ---- edge_attr mean partial sums (no atomics) ----
    int idx = b * 256 + t;
    float v = 0.f;
    for (int i = idx; i < NE; i += 65536) v += ea[i];
    for (int off = 1; off < 64; off <<= 1) v += __shfl_xor(v, off, 64);
    if ((t & 63) == 0) sw[t >> 6] = v;
    __syncthreads();
    if (t == 0) partials[b] = sw[0] + sw[1] + sw[2] + sw[3];
    return;
  }
  b -= MEAN_BLKS;
  if (b < ENC_BLKS) {  // ---- encoder: h0 = relu(x @ enc_w + enc_b), bf16 ----
    int i = b * 256 + t;  // exactly NN*64
    int n = i >> 6, j = i & 63;
    float acc = enc_b[j];
#pragma unroll
    for (int k = 0; k < 8; k++) acc += x[n * 8 + k] * enc_w[k * 64 + j];
    h0[i] = f2bf(fmaxf(acc, 0.f));
    return;
  }
  b -= ENC_BLKS;
  if (b < WCONV_BLKS) {  // ---- weight converts f32 [K][256] -> bf16 [256][K] ----
    if (b < 128) {
      int sec = b >> 6;
      const float* W = sec ? g1_wr : g1_wl;
      ushort* Wt = sec ? w1r : w1l;
      int i = (b & 63) * 256 + t;
      int n = i >> 6, k = i & 63;
      Wt[i] = f2bf(W[(size_t)k * 256 + n]);
    } else {
      int bb = b - 128;
      int sec = bb >> 8;
      const float* W = sec ? g2_wr : g2_wl;
      ushort* Wt = sec ? w2r : w2l;
      int i = (bb & 255) * 256 + t;
      int n = i >> 8, k = i & 255;
      Wt[i] = f2bf(W[(size_t)k * 256 + n]);
    }
    return;
  }
  b -= WCONV_BLKS;
  if (b == 0) {  // ---- att pre-scale ----
    const float L2E = 1.44269504f;
    float v1 = att1[t], v2 = att2[t];
    a06_1[t] = 0.6f * L2E * v1;
    a04_1[t] = 0.4f * L2E * v1;
    a06_2[t] = 0.6f * L2E * v2;
    a04_2[t] = 0.4f * L2E * v2;
    return;
  }
  b -= 1;
  {  // ---- zero sums+cnts (contiguous region of NB*256+NB floats) ----
    int i = b * 256 + t;
    if (i < NB * 256 + NB) zero_region[i] = 0.f;
  }
}

// ---------- dual linear via MFMA + async LDS-staged A + optional fused sort ----
// A-tile (32 x K) is staged global->LDS via global_load_lds (width 16), double
// buffered: the next tile's stage is issued BEFORE the current tile's compute,
// so HBM/L2 latency hides under ~1500cy of MFMA. All 4 waves share the staged
// A (4x reuse). Bank conflicts on the stride-K fragment reads are removed by a
// both-sides XOR swizzle (per-lane GLOBAL source permutation col16^=row&7 with
// linear LDS dest; same XOR applied on the ds_read side — an involution).
template <int K, bool WITH_SORT>
__global__ __launch_bounds__(256) void dual_linear_pb(
    const ushort* __restrict__ A, const ushort* __restrict__ Wl,
    const ushort* __restrict__ Wr, const float* __restrict__ bl,
    const float* __restrict__ br, ushort* __restrict__ xl,
    ushort* __restrict__ xr,
    const int* __restrict__ gcursor, const float* __restrict__ partials,
    const int2* __restrict__ bucketed, int2* __restrict__ sedge,
    int* __restrict__ offsets, int* __restrict__ counts) {
  constexpr int C16 = K / 8;           // 16B chunks per A row
  constexpr int ABUF_USH = 32 * K;     // ushorts per A buffer
  constexpr int GEMM_SMEM = 2 * ABUF_USH * 2 + 32 * 272 * 2;
  constexpr int ARENA = (WITH_SORT && GEMM_SMEM < SORT_SMEM) ? SORT_SMEM : GEMM_SMEM;
  __shared__ __align__(16) char smem[ARENA];
  int t = threadIdx.x;
  if (WITH_SORT && blockIdx.x >= GEMM_GX) {
    if (blockIdx.y != 0) return;
    // ======== bucket sort pass 2 (all-LDS), patches self-loop ea ========
    int2* stage = (int2*)smem;                     // CAP
    int* hist = (int*)(smem + CAP * 8);            // 256
    int* scn = hist + 256;                         // 256
    int* cur = scn + 256;                          // 256
    float* sw = (float*)(cur + 256);               // 4
    int b = blockIdx.x - GEMM_GX;
    float pv = partials[t];
    for (int off = 1; off < 64; off <<= 1) pv += __shfl_xor(pv, off, 64);
    if ((t & 63) == 0) sw[t >> 6] = pv;
    hist[t] = 0;
    __syncthreads();
    int meanb = __float_as_int((sw[0] + sw[1] + sw[2] + sw[3]) * (1.0f / NE));
    int base = b * CAP;
    int nb = min(gcursor[b], CAP - 16);
    for (int i = t; i < nb; i += 256) {
      int2 s = bucketed[base + i];
      if (s.x & SELF_FLAG) s.y = meanb;  // patch self-loop ea to mean
      stage[i] = s;
    }
    __syncthreads();
    if (t < 16) {  // pad entries (masked in gat; always-valid prefetch reads)
      int2 pv2 = make_int2((stage[0].x & 0xFFFF) << 9, stage[0].y);
      sedge[base + nb + t] = pv2;
    }
    for (int i = t; i < nb; i += 256) atomicAdd(&hist[(stage[i].x >> 16) & 255], 1);
    __syncthreads();
    int v = hist[t];
    scn[t] = v;
    __syncthreads();
    for (int off = 1; off < 256; off <<= 1) {
      int add = (t >= off) ? scn[t - off] : 0;
      __syncthreads();
      scn[t] += add;
      __syncthreads();
    }
    int excl = scn[t] - v;
    cur[t] = excl;
    __syncthreads();
    for (int i = t; i < nb; i += 256) {
      int dl = (stage[i].x >> 16) & 255;
      int p = atomicAdd(&cur[dl], 1);
      sedge[base + p] = make_int2((stage[i].x & 0xFFFF) << 9, stage[i].y);
    }
    int d = b * 256 + t;
    if (d < NN) {
      offsets[d] = base + excl;
      counts[d] = v;
    }
    return;
  }
  // ======== GEMM ========
  ushort* abuf = (ushort*)smem;  // 2 x 32*K (double-buffered A tile)
  ushort(*lt)[272] = reinterpret_cast<ushort(*)[272]>(smem + (size_t)2 * ABUF_USH * 2);
  int wave = t >> 6, lane = t & 63;
  int lr = lane & 15;        // row-in-frag (A) / col-in-frag (B/D)
  int kb = (lane >> 4) * 8;  // k-base (halves) within 32-wide k-step
  const ushort* W = blockIdx.y ? Wr : Wl;
  const float* bias = blockIdx.y ? br : bl;
  ushort* O = blockIdx.y ? xr : xl;
  const int c0 = wave * 64;
  const ushort* pb = W + (size_t)(c0 + lr) * K + kb;
  int cb = (t & 31) * 8;  // col base for the coalesced write phase

  // stage tile rows rr..rr+31 into A-buffer bi (swizzled global src, linear dest)
  auto STAGE = [&](int bi, int rr) {
#pragma unroll
    for (int i = 0; i < K / 64; i++) {
      int s = i * 256 + wave * 64 + lane;  // 16B slot
      int row = s / C16;
      int colg = (s % C16) ^ (row & 7);
      const ushort* g = A + (size_t)(rr + row) * K + colg * 8;
      ushort* l = abuf + (size_t)bi * ABUF_USH + (size_t)(i * 256 + wave * 64) * 8;
      __builtin_amdgcn_global_load_lds(
          (const __attribute__((address_space(1))) unsigned*)g,
          (__attribute__((address_space(3))) unsigned*)l, 16, 0, 0);
    }
  };

  int cur = 0;
  STAGE(0, blockIdx.x * 32);
  __syncthreads();  // drains vmcnt -> buf0 ready
  for (int tt = blockIdx.x; tt < NTILES; tt += GEMM_GX) {
    int nxt = tt + GEMM_GX;
    if (nxt < NTILES) STAGE(cur ^ 1, nxt * 32);  // async; completes before epilogue barrier
    int r = tt * 32;
    const ushort* ab = abuf + (size_t)cur * ABUF_USH;
    f32x4 acc[2][4];
#pragma unroll
    for (int fr = 0; fr < 2; fr++)
#pragma unroll
      for (int fc = 0; fc < 4; fc++) acc[fr][fc] = (f32x4){0.f, 0.f, 0.f, 0.f};
#pragma unroll
    for (int kc = 0; kc < K; kc += 64) {
      int c16a = (kb + kc) >> 3;
      int c16b = (kb + kc + 32) >> 3;
      int lr2 = lr + 16;
      short8 a00 = *(const short8*)(ab + (size_t)(lr * C16 + (c16a ^ (lr & 7))) * 8);
      short8 a01 = *(const short8*)(ab + (size_t)(lr * C16 + (c16b ^ (lr & 7))) * 8);
      short8 a10 = *(const short8*)(ab + (size_t)(lr2 * C16 + (c16a ^ (lr2 & 7))) * 8);
      short8 a11 = *(const short8*)(ab + (size_t)(lr2 * C16 + (c16b ^ (lr2 & 7))) * 8);
      short8 b0[4], b1[4];
#pragma unroll
      for (int fc = 0; fc < 4; fc++) {
        b0[fc] = *(const short8*)(pb + (size_t)fc * 16 * K + kc);
        b1[fc] = *(const short8*)(pb + (size_t)fc * 16 * K + kc + 32);
      }
#pragma unroll
      for (int fc = 0; fc < 4; fc++) {
        acc[0][fc] = __builtin_amdgcn_mfma_f32_16x16x32_bf16(a00, b0[fc], acc[0][fc], 0, 0, 0);
        acc[1][fc] = __builtin_amdgcn_mfma_f32_16x16x32_bf16(a10, b0[fc], acc[1][fc], 0, 0, 0);
      }
#pragma unroll
      for (int fc = 0; fc < 4; fc++) {
        acc[0][fc] = __builtin_amdgcn_mfma_f32_16x16x32_bf16(a01, b1[fc], acc[0][fc], 0, 0, 0);
        acc[1][fc] = __builtin_amdgcn_mfma_f32_16x16x32_bf16(a11, b1[fc], acc[1][fc], 0, 0, 0);
      }
    }
    // stage bf16 subtile to LDS, XOR-swizzled: col' = col ^ (((row>>2)&3)<<4)
#pragma unroll
    for (int fc = 0; fc < 4; fc++) {
      int c = c0 + fc * 16 + lr;
      float bv = bias[c];
#pragma unroll
      for (int fr = 0; fr < 2; fr++) {
#pragma unroll
        for (int j = 0; j < 4; j++) {
          int row = fr * 16 + (lane >> 4) * 4 + j;
          int cs = c ^ (((row >> 2) & 3) << 4);
          lt[row][cs] = f2bf(acc[fr][fc][j] + bv);
        }
      }
    }
    __syncthreads();  // also drains the in-flight next-tile stage (vmcnt)
    // coalesced write: 256 threads x 4 iters; each row written as contiguous 512B
#pragma unroll
    for (int it = 0; it < 4; it++) {
      int rl = (t >> 5) + it * 8;
      int row = r + rl;
      if (row < NN) {
        int cs = cb ^ (((rl >> 2) & 3) << 4);
        short8 v = *(const short8*)&lt[rl][cs];
        *(short8*)(O + (size_t)row * 256 + cb) = v;
      }
    }
    __syncthreads();
    cur ^= 1;
  }
}

// ================= fused GATv2 edge phase (4-wide, branchless, 2-deep pipe) ====
__global__ __launch_bounds__(256) void gat_fused_kernel(const int* __restrict__ offsets,
                                                        const int* __restrict__ counts,
                                                        const int2* __restrict__ sedge,
                                                        const ushort* __restrict__ xl,
                                                        const ushort* __restrict__ xr,
                                                        const float* __restrict__ we,
                                                        const float* __restrict__ a06p,
                                                        const float* __restrict__ a04p,
                                                        const float* __restrict__ bias,
                                                        ushort* __restrict__ hb) {
  int w = threadIdx.x >> 6, lane = threadIdx.x & 63;
  int d = blockIdx.x * 4 + w;
  if (d >= NN) return;
  int off = offsets[d], cnt = counts[d];
  const int c4 = lane * 4;
  ushort4 xru = *(const ushort4*)(xr + (size_t)d * 256 + c4);
  const float4 xr4 = {bf2f(xru.x), bf2f(xru.y), bf2f(xru.z), bf2f(xru.w)};
  const float4 we4 = *(const float4*)(we + c4);
  const float4 a06 = *(const float4*)(a06p + c4);
  const float4 a04 = *(const float4*)(a04p + c4);
  float4 acc = {0.f, 0.f, 0.f, 0.f};
  float den = 0.f;
  const int2* pe = sedge + off;
  const char* xlc = (const char*)xl + (size_t)c4 * 2;  // sedge.x is byte offset
  int2 e0 = pe[0], e1 = pe[1], e2 = pe[2], e3 = pe[3];
  ushort4 xu0 = *(const ushort4*)(xlc + (size_t)(unsigned)e0.x);
  ushort4 xu1 = *(const ushort4*)(xlc + (size_t)(unsigned)e1.x);
  ushort4 xu2 = *(const ushort4*)(xlc + (size_t)(unsigned)e2.x);
  ushort4 xu3 = *(const ushort4*)(xlc + (size_t)(unsigned)e3.x);
  int2 f0 = pe[4], f1 = pe[5], f2 = pe[6], f3 = pe[7];
  ushort4 yu0 = *(const ushort4*)(xlc + (size_t)(unsigned)f0.x);
  ushort4 yu1 = *(const ushort4*)(xlc + (size_t)(unsigned)f1.x);
  ushort4 yu2 = *(const ushort4*)(xlc + (size_t)(unsigned)f2.x);
  ushort4 yu3 = *(const ushort4*)(xlc + (size_t)(unsigned)f3.x);
#pragma unroll 2
  for (int i = 0; i < cnt; i += 4) {
    float ce0 = __int_as_float(e0.y), ce1 = __int_as_float(e1.y);
    float ce2 = __int_as_float(e2.y), ce3 = __int_as_float(e3.y);
    float4 x0 = {bf2f(xu0.x), bf2f(xu0.y), bf2f(xu0.z), bf2f(xu0.w)};
    float4 x1 = {bf2f(xu1.x), bf2f(xu1.y), bf2f(xu1.z), bf2f(xu1.w)};
    float4 x2 = {bf2f(xu2.x), bf2f(xu2.y), bf2f(xu2.z), bf2f(xu2.w)};
    float4 x3 = {bf2f(xu3.x), bf2f(xu3.y), bf2f(xu3.z), bf2f(xu3.w)};
    e0 = f0; e1 = f1; e2 = f2; e3 = f3;
    xu0 = yu0; xu1 = yu1; xu2 = yu2; xu3 = yu3;
    f0 = pe[i + 8]; f1 = pe[i + 9]; f2 = pe[i + 10]; f3 = pe[i + 11];
    yu0 = *(const ushort4*)(xlc + (size_t)(unsigned)f0.x);
    yu1 = *(const ushort4*)(xlc + (size_t)(unsigned)f1.x);
    yu2 = *(const ushort4*)(xlc + (size_t)(unsigned)f2.x);
    yu3 = *(const ushort4*)(xlc + (size_t)(unsigned)f3.x);
    float v0, v1, v2, v3;
    float p0, p1, p2, p3;
    v0 = x0.x + fmaf(ce0, we4.x, xr4.x);
    v1 = x0.y + fmaf(ce0, we4.y, xr4.y);
    v2 = x0.z + fmaf(ce0, we4.z, xr4.z);
    v3 = x0.w + fmaf(ce0, we4.w, xr4.w);
    p0 = fmaf(a06.x, v0, a04.x * fabsf(v0));
    p0 = fmaf(a06.y, v1, fmaf(a04.y, fabsf(v1), p0));
    p0 = fmaf(a06.z, v2, fmaf(a04.z, fabsf(v2), p0));
    p0 = fmaf(a06.w, v3, fmaf(a04.w, fabsf(v3), p0));
    v0 = x1.x + fmaf(ce1, we4.x, xr4.x);
    v1 = x1.y + fmaf(ce1, we4.y, xr4.y);
    v2 = x1.z + fmaf(ce1, we4.z, xr4.z);
    v3 = x1.w + fmaf(ce1, we4.w, xr4.w);
    p1 = fmaf(a06.x, v0, a04.x * fabsf(v0));
    p1 = fmaf(a06.y, v1, fmaf(a04.y, fabsf(v1), p1));
    p1 = fmaf(a06.z, v2, fmaf(a04.z, fabsf(v2), p1));
    p1 = fmaf(a06.w, v3, fmaf(a04.w, fabsf(v3), p1));
    v0 = x2.x + fmaf(ce2, we4.x, xr4.x);
    v1 = x2.y + fmaf(ce2, we4.y, xr4.y);
    v2 = x2.z + fmaf(ce2, we4.z, xr4.z);
    v3 = x2.w + fmaf(ce2, we4.w, xr4.w);
    p2 = fmaf(a06.x, v0, a04.x * fabsf(v0));
    p2 = fmaf(a06.y, v1, fmaf(a04.y, fabsf(v1), p2));
    p2 = fmaf(a06.z, v2, fmaf(a04.z, fabsf(v2), p2));
    p2 = fmaf(a06.w, v3, fmaf(a04.w, fabsf(v3), p2));
    v0 = x3.x + fmaf(ce3, we4.x, xr4.x);
    v1 = x3.y + fmaf(ce3, we4.y, xr4.y);
    v2 = x3.z + fmaf(ce3, we4.z, xr4.z);
    v3 = x3.w + fmaf(ce3, we4.w, xr4.w);
    p3 = fmaf(a06.x, v0, a04.x * fabsf(v0));
    p3 = fmaf(a06.y, v1, fmaf(a04.y, fabsf(v1), p3));
    p3 = fmaf(a06.z, v2, fmaf(a04.z, fabsf(v2), p3));
    p3 = fmaf(a06.w, v3, fmaf(a04.w, fabsf(v3), p3));
    p0 = row_reduce16(p0);
    p1 = row_reduce16(p1);
    p2 = row_reduce16(p2);
    p3 = row_reduce16(p3);
    float ex0 = exp2s(fminf(p0, 120.f));
    float ex1 = exp2s(fminf(p1, 120.f));
    float ex2 = exp2s(fminf(p2, 120.f));
    float ex3 = exp2s(fminf(p3, 120.f));
    ex1 = (i + 1 < cnt) ? ex1 : 0.f;  // wave-uniform tail masks
    ex2 = (i + 2 < cnt) ? ex2 : 0.f;
    ex3 = (i + 3 < cnt) ? ex3 : 0.f;
    den += (ex0 + ex1) + (ex2 + ex3);
    acc.x = fmaf(x0.x, ex0, fmaf(x1.x, ex1, fmaf(x2.x, ex2, fmaf(x3.x, ex3, acc.x))));
    acc.y = fmaf(x0.y, ex0, fmaf(x1.y, ex1, fmaf(x2.y, ex2, fmaf(x3.y, ex3, acc.y))));
    acc.z = fmaf(x0.z, ex0, fmaf(x1.z, ex1, fmaf(x2.z, ex2, fmaf(x3.z, ex3, acc.z))));
    acc.w = fmaf(x0.w, ex0, fmaf(x1.w, ex1, fmaf(x2.w, ex2, fmaf(x3.w, ex3, acc.w))));
  }
  const float4 b4 = *(const float4*)(bias + c4);
  float inv = 1.f / den;  // every node has a self-loop -> den > 0
  ushort4 o;
  o.x = f2bf(fmaxf(fmaf(acc.x, inv, b4.x), 0.f));
  o.y = f2bf(fmaxf(fmaf(acc.y, inv, b4.y), 0.f));
  o.z = f2bf(fmaxf(fmaf(acc.z, inv, b4.z), 0.f));
  o.w = f2bf(fmaxf(fmaf(acc.w, inv, b4.w), 0.f));
  *(ushort4*)(hb + (size_t)d * 256 + c4) = o;
}

// ---------- global mean pool (batch is sorted; run-length flush) ----------
__global__ __launch_bounds__(256) void pool_kernel(const ushort* __restrict__ h,
                                                   const int* __restrict__ batch,
                                                   float* __restrict__ sums,
                                                   float* __restrict__ cnts) {
  __shared__ int sb[128];
  int n0 = blockIdx.x * 128;
  int j = threadIdx.x;
  int count = min(128, NN - n0);
  if (count <= 0) return;
  for (int t = threadIdx.x; t < count; t += 256) sb[t] = batch[n0 + t];
  __syncthreads();
  float acc = 0.f;
  int run = 0;
  int cur = sb[0];
  for (int i = 0; i < count; ++i) {
    int b = sb[i];
    if (b != cur) {
      atomicAdd(&sums[(size_t)cur * 256 + j], acc);
      if (j == 0) atomicAdd(&cnts[cur], (float)run);
      acc = 0.f;
      run = 0;
      cur = b;
    }
    acc += bf2f(h[(size_t)(n0 + i) * 256 + j]);
    run++;
  }
  atomicAdd(&sums[(size_t)cur * 256 + j], acc);
  if (j == 0) atomicAdd(&cnts[cur], (float)run);
}

// ---------- post-MLP head: one block per graph ----------
__global__ __launch_bounds__(128) void head_kernel(const float* __restrict__ sums,
                                                   const float* __restrict__ cnts,
                                                   const float* __restrict__ p1_w,
                                                   const float* __restrict__ p1_b,
                                                   const float* __restrict__ ln_g,
                                                   const float* __restrict__ ln_b,
                                                   const float* __restrict__ p2_w,
                                                   const float* __restrict__ p2_b,
                                                   const float* __restrict__ hc_w,
                                                   const float* __restrict__ hc_b,
                                                   const float* __restrict__ hf_w,
                                                   const float* __restrict__ hf_b,
                                                   float* __restrict__ out) {
  int g = blockIdx.x;
  int j = threadIdx.x;  // 0..127
  __shared__ float sp[256], st[128], sz[64];
  float cnt = fmaxf(cnts[g], 1.0f);
  for (int t = j; t < 256; t += 128) sp[t] = sums[(size_t)g * 256 + t] / cnt;
  __syncthreads();
  float acc = p1_b[j];
  for (int k = 0; k < 256; k++) acc += sp[k] * p1_w[(size_t)k * 128 + j];
  st[j] = acc;
  __syncthreads();
  float mu = 0.f;
  for (int k = 0; k < 128; k++) mu += st[k];
  mu *= (1.f / 128.f);
  float var = 0.f;
  for (int k = 0; k < 128; k++) {
    float d = st[k] - mu;
    var += d * d;
  }
  var *= (1.f / 128.f);
  float tj = (acc - mu) * rsqrtf(var + 1e-5f) * ln_g[j] + ln_b[j];
  tj = fmaxf(tj, 0.f);
  __syncthreads();
  st[j] = tj;
  __syncthreads();
  if (j < 64) {
    float z = p2_b[j];
    for (int k = 0; k < 128; k++) z += st[k] * p2_w[(size_t)k * 64 + j];
    z = fmaxf(z, 0.f);
    sz[j] = z;
    out[500 + (size_t)g * 64 + j] = z;  // output 2: z [B,64]
  }
  __syncthreads();
  if (j == 0) {
    float c = hc_b[0];
    for (int k = 0; k < 64; k++) c += sz[k] * hc_w[k];
    out[g] = c;  // output 0: cooling [B]
  }
  if (j >= 1 && j < 10) {
    int f = j - 1;
    float v = hf_b[f];
    for (int k = 0; k < 64; k++) v += sz[k] * hf_w[(size_t)k * 9 + f];
    out[50 + (size_t)g * 9 + f] = v;  // output 1: fatigue [B,9]
  }
}

extern "C" void kernel_launch(void* const* d_in, const int* in_sizes, int n_in,
                              void* d_out, int out_size, void* d_ws, size_t ws_size,
                              hipStream_t stream) {
  const float* x = (const float*)d_in[0];
  const int* ei = (const int*)d_in[1];
  const float* ea = (const float*)d_in[2];
  const int* batch = (const int*)d_in[3];
  const float* enc_w = (const float*)d_in[4];
  const float* enc_b = (const float*)d_in[5];
  const float* g1_wl = (const float*)d_in[6];
  const float* g1_bl = (const float*)d_in[7];
  const float* g1_wr = (const float*)d_in[8];
  const float* g1_br = (const float*)d_in[9];
  const float* g1_we = (const float*)d_in[10];
  const float* g1_att = (const float*)d_in[11];
  const float* g1_bias = (const float*)d_in[12];
  const float* g2_wl = (const float*)d_in[13];
  const float* g2_bl = (const float*)d_in[14];
  const float* g2_wr = (const float*)d_in[15];
  const float* g2_br = (const float*)d_in[16];
  const float* g2_we = (const float*)d_in[17];
  const float* g2_att = (const float*)d_in[18];
  const float* g2_bias = (const float*)d_in[19];
  const float* p1_w = (const float*)d_in[20];
  const float* p1_b = (const float*)d_in[21];
  const float* ln_g = (const float*)d_in[22];
  const float* ln_b = (const float*)d_in[23];
  const float* p2_w = (const float*)d_in[24];
  const float* p2_b = (const float*)d_in[25];
  const float* hc_w = (const float*)d_in[26];
  const float* hc_b = (const float*)d_in[27];
  const float* hf_w = (const float*)d_in[28];
  const float* hf_b = (const float*)d_in[29];
  float* out = (float*)d_out;

  // ---- workspace layout ----
  ushort* xlb = (ushort*)d_ws;                    // N*256 bf16
  ushort* xrb = xlb + (size_t)NN * 256;           // N*256 bf16
  ushort* hb = xrb + (size_t)NN * 256;            // N*256 bf16
  ushort* h0b = hb + (size_t)NN * 256;            // N*64 bf16
  ushort* w1l = h0b + (size_t)NN * 64;            // 256*64 bf16 (transposed)
  ushort* w1r = w1l + 256 * 64;
  ushort* w2l = w1r + 256 * 64;                   // 256*256 bf16
  ushort* w2r = w2l + 256 * 256;
  int2* bucketed = (int2*)(w2r + 256 * 256);      // NBKT*CAP (pass-1 output)
  int2* sedge = bucketed + (size_t)NBKT * CAP;    // NBKT*CAP (sorted + pads)
  int* gcursor = (int*)(sedge + (size_t)NBKT * CAP);  // NBKT (zeroed below)
  int* counts = gcursor + NBKT;                   // NN
  int* offsets = counts + NN;                     // NN
  float* sums = (float*)(offsets + NN);           // B*256 (zeroed in setup)
  float* cnts = sums + (size_t)NB * 256;          // B    (zeroed in setup)
  float* partials = cnts + NB;                    // 256
  float* a06_1 = partials + 256;                  // 256
  float* a04_1 = a06_1 + 256;                     // 256
  float* a06_2 = a04_1 + 256;                     // 256
  float* a04_2 = a06_2 + 256;                     // 256

  // ---- gcursor = per-bucket fill counters (must be 0 before setup) ----
  hipMemsetAsync(gcursor, 0, NBKT * sizeof(int), stream);

  // ---- mega setup (bucket pass-1 + mean partials + encoder + wconv + att + zeros) ----
  setup_kernel<<<SETUP_GRID, 256, 0, stream>>>(
      x, enc_w, enc_b, h0b, ea, partials, ei, gcursor, bucketed,
      g1_wl, g1_wr, g2_wl, g2_wr, w1l, w1r, w2l, w2r,
      g1_att, g2_att, a06_1, a04_1, a06_2, a04_2, sums);

  const int nGatBlocks = (NN + 3) / 4;

  // ========== GAT layer 1 (K=64) — GEMM fused with bucket-sort pass 2 ==========
  dim3 g64(GEMM_GX + NBKT, 2);
  dual_linear_pb<64, true><<<g64, 256, 0, stream>>>(
      h0b, w1l, w1r, g1_bl, g1_br, xlb, xrb,
      gcursor, partials, bucketed, sedge, offsets, counts);
  gat_fused_kernel<<<nGatBlocks, 256, 0, stream>>>(offsets, counts, sedge, xlb, xrb,
                                                   g1_we, a06_1, a04_1, g1_bias, hb);

  // ================= GAT layer 2 (K=256) =================
  dim3 g256(GEMM_GX, 2);
  dual_linear_pb<256, false><<<g256, 256, 0, stream>>>(
      hb, w2l, w2r, g2_bl, g2_br, xlb, xrb,
      gcursor, partials, bucketed, sedge, offsets, counts);
  gat_fused_kernel<<<nGatBlocks, 256, 0, stream>>>(offsets, counts, sedge, xlb, xrb,
                                                   g2_we, a06_2, a04_2, g2_bias, hb);

  // ================= pool + head =================
  pool_kernel<<<(NN + 127) / 128, 256, 0, stream>>>(hb, batch, sums, cnts);
  head_kernel<<<NB, 128, 0, stream>>>(sums, cnts, p1_w, p1_b, ln_g, ln_b, p2_w, p2_b,
                                      hc_w, hc_b, hf_w, hf_b, out);
}